// Round 1
// baseline (1274.930 us; speedup 1.0000x reference)
//
#include <hip/hip_runtime.h>
#include <math.h>

#define N_FEAT 128
#define N_CLASSES 40

// ---------------- CSR build ----------------

__global__ void zero_i32(int* __restrict__ p, int n) {
    int i = blockIdx.x * blockDim.x + threadIdx.x;
    if (i < n) p[i] = 0;
}

__global__ void hist_kernel(const int* __restrict__ dst, int* __restrict__ cnt, int E) {
    int e = blockIdx.x * blockDim.x + threadIdx.x;
    if (e < E) atomicAdd(&cnt[dst[e]], 1);
}

__global__ void dinv_kernel(const int* __restrict__ cnt, float* __restrict__ dinv, int n) {
    int i = blockIdx.x * blockDim.x + threadIdx.x;
    if (i < n) dinv[i] = rsqrtf((float)(cnt[i] + 1));   // +1 = self-loop
}

// Single-block exclusive scan over n counts -> rowptr[0..n], rowptr[n] = total.
__global__ void scan_kernel(const int* __restrict__ cnt, int* __restrict__ rowptr, int n) {
    __shared__ int part[1024];
    int t = threadIdx.x;
    int chunk = (n + 1023) / 1024;
    int beg = t * chunk;
    int end = beg + chunk; if (end > n) end = n;
    if (beg > n) beg = n;
    int s = 0;
    for (int i = beg; i < end; i++) s += cnt[i];
    part[t] = s;
    __syncthreads();
    // Hillis-Steele inclusive scan
    for (int off = 1; off < 1024; off <<= 1) {
        int v = part[t];
        int u = (t >= off) ? part[t - off] : 0;
        __syncthreads();
        part[t] = v + u;
        __syncthreads();
    }
    int excl = part[t] - s;
    int run = excl;
    for (int i = beg; i < end; i++) { rowptr[i] = run; run += cnt[i]; }
    if (t == 1023) rowptr[n] = part[1023];
}

__global__ void fill_kernel(const int* __restrict__ src, const int* __restrict__ dst,
                            const int* __restrict__ rowptr, int* __restrict__ counter,
                            const float* __restrict__ dinv,
                            int* __restrict__ colidx, float* __restrict__ coef, int E) {
    int e = blockIdx.x * blockDim.x + threadIdx.x;
    if (e < E) {
        int d = dst[e], s = src[e];
        int pos = rowptr[d] + atomicAdd(&counter[d], 1);
        colidx[pos] = s;
        coef[pos] = dinv[s] * dinv[d];
    }
}

// ---------------- GEMM: [nrows,128] @ [128,128] -> [nrows,128] ----------------
// block 256 threads, tile 64 rows x 128 cols, BK=32, micro-tile 4x8 per thread.

__global__ void gemm128(const float* __restrict__ X, const float* __restrict__ W,
                        float* __restrict__ H, int nrows) {
    __shared__ float As[64][33];
    __shared__ float Bs[32][129];
    int block_row = blockIdx.x * 64;
    int tid = threadIdx.x;
    int tx = tid & 15;   // col group: 16 x 8 = 128 cols
    int ty = tid >> 4;   // row group: 16 x 4 = 64 rows
    float acc[4][8];
    #pragma unroll
    for (int i = 0; i < 4; i++)
        #pragma unroll
        for (int j = 0; j < 8; j++) acc[i][j] = 0.f;

    for (int k0 = 0; k0 < 128; k0 += 32) {
        // A tile: 64x32 = 512 float4, 2 per thread
        #pragma unroll
        for (int l = tid; l < 512; l += 256) {
            int r = l >> 3, c4 = l & 7;
            int gr = block_row + r;
            float4 v = make_float4(0.f, 0.f, 0.f, 0.f);
            if (gr < nrows) v = *(const float4*)&X[(size_t)gr * 128 + k0 + c4 * 4];
            As[r][c4 * 4 + 0] = v.x; As[r][c4 * 4 + 1] = v.y;
            As[r][c4 * 4 + 2] = v.z; As[r][c4 * 4 + 3] = v.w;
        }
        // B tile: 32x128 = 1024 float4, 4 per thread
        #pragma unroll
        for (int l = tid; l < 1024; l += 256) {
            int r = l >> 5, c4 = l & 31;
            float4 v = *(const float4*)&W[(size_t)(k0 + r) * 128 + c4 * 4];
            Bs[r][c4 * 4 + 0] = v.x; Bs[r][c4 * 4 + 1] = v.y;
            Bs[r][c4 * 4 + 2] = v.z; Bs[r][c4 * 4 + 3] = v.w;
        }
        __syncthreads();
        #pragma unroll
        for (int kk = 0; kk < 32; kk++) {
            float a[4], b[8];
            #pragma unroll
            for (int i = 0; i < 4; i++) a[i] = As[ty * 4 + i][kk];
            #pragma unroll
            for (int j = 0; j < 8; j++) b[j] = Bs[kk][tx * 8 + j];
            #pragma unroll
            for (int i = 0; i < 4; i++)
                #pragma unroll
                for (int j = 0; j < 8; j++) acc[i][j] += a[i] * b[j];
        }
        __syncthreads();
    }
    #pragma unroll
    for (int i = 0; i < 4; i++) {
        int gr = block_row + ty * 4 + i;
        if (gr < nrows) {
            float4 v0 = make_float4(acc[i][0], acc[i][1], acc[i][2], acc[i][3]);
            float4 v1 = make_float4(acc[i][4], acc[i][5], acc[i][6], acc[i][7]);
            *(float4*)&H[(size_t)gr * 128 + tx * 8 + 0] = v0;
            *(float4*)&H[(size_t)gr * 128 + tx * 8 + 4] = v1;
        }
    }
}

// ---------------- GEMM3: [nrows,128] @ [128,40] -> [nrows,40] ----------------
// one wave per row; lanes 0..39 compute one output col each.

__global__ void gemm40(const float* __restrict__ H, const float* __restrict__ W3,
                       float* __restrict__ O, int nrows) {
    __shared__ float Ws[128 * N_CLASSES];
    for (int l = threadIdx.x; l < 128 * N_CLASSES; l += blockDim.x) Ws[l] = W3[l];
    __syncthreads();
    int wave = threadIdx.x >> 6;
    int lane = threadIdx.x & 63;
    int row = blockIdx.x * (blockDim.x >> 6) + wave;
    if (row >= nrows) return;
    if (lane < N_CLASSES) {
        const float* hrow = &H[(size_t)row * 128];
        float acc = 0.f;
        #pragma unroll 8
        for (int k = 0; k < 128; k++) acc += hrow[k] * Ws[k * N_CLASSES + lane];
        O[(size_t)row * N_CLASSES + lane] = acc;
    }
}

// ---------------- Aggregation (128-wide): pull over CSR + self-loop + bias (+relu) ----

template <int RELU>
__global__ void agg128(const float* __restrict__ H, const int* __restrict__ rowptr,
                       const int* __restrict__ colidx, const float* __restrict__ coef,
                       const float* __restrict__ dinv, const float* __restrict__ bias,
                       float* __restrict__ O, int nrows) {
    int wave = threadIdx.x >> 6;
    int lane = threadIdx.x & 63;
    int node = blockIdx.x * (blockDim.x >> 6) + wave;
    if (node >= nrows) return;
    int beg = rowptr[node], end = rowptr[node + 1];
    float di = dinv[node];
    float cs = di * di;
    float2 hv = ((const float2*)&H[(size_t)node * 128])[lane];
    float ax = cs * hv.x, ay = cs * hv.y;
    for (int j = beg; j < end; j++) {
        int s = colidx[j];
        float c = coef[j];
        float2 v = ((const float2*)&H[(size_t)s * 128])[lane];
        ax += c * v.x; ay += c * v.y;
    }
    float2 b = ((const float2*)bias)[lane];
    ax += b.x; ay += b.y;
    if (RELU) { ax = fmaxf(ax, 0.f); ay = fmaxf(ay, 0.f); }
    float2 r; r.x = ax; r.y = ay;
    ((float2*)&O[(size_t)node * 128])[lane] = r;
}

// ---------------- Aggregation (40-wide) + bias + log_softmax fused ----------------

__global__ void agg40_lsm(const float* __restrict__ H, const int* __restrict__ rowptr,
                          const int* __restrict__ colidx, const float* __restrict__ coef,
                          const float* __restrict__ dinv, const float* __restrict__ bias,
                          float* __restrict__ out, int nrows) {
    int wave = threadIdx.x >> 6;
    int lane = threadIdx.x & 63;
    int node = blockIdx.x * (blockDim.x >> 6) + wave;
    if (node >= nrows) return;
    int beg = rowptr[node], end = rowptr[node + 1];
    float di = dinv[node];
    float acc = 0.f;
    if (lane < N_CLASSES) acc = di * di * H[(size_t)node * N_CLASSES + lane];
    for (int j = beg; j < end; j++) {
        int s = colidx[j];
        float c = coef[j];
        if (lane < N_CLASSES) acc += c * H[(size_t)s * N_CLASSES + lane];
    }
    if (lane < N_CLASSES) acc += bias[lane];
    // log_softmax across 40 classes (wave-wide shuffle reduce)
    float m = (lane < N_CLASSES) ? acc : -INFINITY;
    #pragma unroll
    for (int off = 32; off > 0; off >>= 1) m = fmaxf(m, __shfl_xor(m, off));
    float e = (lane < N_CLASSES) ? expf(acc - m) : 0.f;
    #pragma unroll
    for (int off = 32; off > 0; off >>= 1) e += __shfl_xor(e, off);
    float ls = logf(e);
    if (lane < N_CLASSES) out[(size_t)node * N_CLASSES + lane] = acc - m - ls;
}

// ---------------- launch ----------------

extern "C" void kernel_launch(void* const* d_in, const int* in_sizes, int n_in,
                              void* d_out, int out_size, void* d_ws, size_t ws_size,
                              hipStream_t stream) {
    const float* x  = (const float*)d_in[0];
    const int*   ei = (const int*)d_in[1];
    const float* W1 = (const float*)d_in[2];
    const float* b1 = (const float*)d_in[3];
    const float* W2 = (const float*)d_in[4];
    const float* b2 = (const float*)d_in[5];
    const float* W3 = (const float*)d_in[6];
    const float* b3 = (const float*)d_in[7];
    float* out = (float*)d_out;

    int N = in_sizes[0] / N_FEAT;
    int E = in_sizes[1] / 2;
    const int* src = ei;
    const int* dst = ei + E;

    char* ws = (char*)d_ws;
    size_t off = 0;
    auto alloc = [&](size_t bytes) -> char* {
        char* p = ws + off;
        off = (off + bytes + 255) & ~(size_t)255;
        return p;
    };
    int*   deg_cnt = (int*)  alloc((size_t)N * 4);
    int*   counter = (int*)  alloc((size_t)N * 4);
    float* dinv    = (float*)alloc((size_t)N * 4);
    int*   rowptr  = (int*)  alloc((size_t)(N + 1) * 4);
    int*   colidx  = (int*)  alloc((size_t)E * 4);
    float* coef    = (float*)alloc((size_t)E * 4);
    float* bufA    = (float*)alloc((size_t)N * 128 * 4);
    float* bufB    = (float*)alloc((size_t)N * 128 * 4);

    int tpb = 256;
    int gN = (N + tpb - 1) / tpb;
    int gE = (E + tpb - 1) / tpb;

    // CSR build
    zero_i32<<<gN, tpb, 0, stream>>>(deg_cnt, N);
    zero_i32<<<gN, tpb, 0, stream>>>(counter, N);
    hist_kernel<<<gE, tpb, 0, stream>>>(dst, deg_cnt, E);
    dinv_kernel<<<gN, tpb, 0, stream>>>(deg_cnt, dinv, N);
    scan_kernel<<<1, 1024, 0, stream>>>(deg_cnt, rowptr, N);
    fill_kernel<<<gE, tpb, 0, stream>>>(src, dst, rowptr, counter, dinv, colidx, coef, E);

    int gGemm = (N + 63) / 64;
    int gAgg  = (N + 3) / 4;   // 4 waves/block, 1 node/wave

    // layer 1
    gemm128<<<gGemm, 256, 0, stream>>>(x, W1, bufA, N);
    agg128<1><<<gAgg, 256, 0, stream>>>(bufA, rowptr, colidx, coef, dinv, b1, bufB, N);
    // layer 2
    gemm128<<<gGemm, 256, 0, stream>>>(bufB, W2, bufA, N);
    agg128<1><<<gAgg, 256, 0, stream>>>(bufA, rowptr, colidx, coef, dinv, b2, bufB, N);
    // layer 3 (reuse bufA as [N,40])
    gemm40<<<gAgg, 256, 0, stream>>>(bufB, W3, bufA, N);
    agg40_lsm<<<gAgg, 256, 0, stream>>>(bufA, rowptr, colidx, coef, dinv, b3, out, N);
}

// Round 2
// 994.029 us; speedup vs baseline: 1.2826x; 1.2826x over previous
//
#include <hip/hip_runtime.h>
#include <math.h>

#define N_FEAT 128
#define N_CLASSES 40

typedef unsigned short u16;
typedef unsigned int u32;

// ---- bf16 helpers (manual RNE pack, cheap unpack) ----
__device__ __forceinline__ u32 f2bf(float f) {
    u32 u = __float_as_uint(f);
    return (u + 0x7fffu + ((u >> 16) & 1u)) >> 16;
}
__device__ __forceinline__ u32 packbf2(float lo, float hi) {
    return f2bf(lo) | (f2bf(hi) << 16);
}
__device__ __forceinline__ float bflo(u32 v) { return __uint_as_float(v << 16); }
__device__ __forceinline__ float bfhi(u32 v) { return __uint_as_float(v & 0xffff0000u); }
__device__ __forceinline__ float bf1(u16 v) { return __uint_as_float(((u32)v) << 16); }

// ---------------- CSR build ----------------

__global__ void zero_i32(int* __restrict__ p, int n) {
    int i = blockIdx.x * blockDim.x + threadIdx.x;
    if (i < n) p[i] = 0;
}

__global__ void hist_kernel(const int* __restrict__ dst, int* __restrict__ cnt, int E) {
    int e = blockIdx.x * blockDim.x + threadIdx.x;
    if (e < E) atomicAdd(&cnt[dst[e]], 1);
}

__global__ void dinv_kernel(const int* __restrict__ cnt, float* __restrict__ dinv, int n) {
    int i = blockIdx.x * blockDim.x + threadIdx.x;
    if (i < n) dinv[i] = rsqrtf((float)(cnt[i] + 1));   // +1 = self-loop
}

// Single-block exclusive scan over n counts -> rowptr[0..n], rowptr[n] = total.
__global__ void scan_kernel(const int* __restrict__ cnt, int* __restrict__ rowptr, int n) {
    __shared__ int part[1024];
    int t = threadIdx.x;
    int chunk = (n + 1023) / 1024;
    int beg = t * chunk;
    int end = beg + chunk; if (end > n) end = n;
    if (beg > n) beg = n;
    int s = 0;
    for (int i = beg; i < end; i++) s += cnt[i];
    part[t] = s;
    __syncthreads();
    for (int off = 1; off < 1024; off <<= 1) {
        int v = part[t];
        int u = (t >= off) ? part[t - off] : 0;
        __syncthreads();
        part[t] = v + u;
        __syncthreads();
    }
    int excl = part[t] - s;
    int run = excl;
    for (int i = beg; i < end; i++) { rowptr[i] = run; run += cnt[i]; }
    if (t == 1023) rowptr[n] = part[1023];
}

__global__ void fill_kernel(const int* __restrict__ src, const int* __restrict__ dst,
                            const int* __restrict__ rowptr, int* __restrict__ counter,
                            const float* __restrict__ dinv,
                            int* __restrict__ colidx, float* __restrict__ coef, int E) {
    int e = blockIdx.x * blockDim.x + threadIdx.x;
    if (e < E) {
        int d = dst[e], s = src[e];
        int pos = rowptr[d] + atomicAdd(&counter[d], 1);
        colidx[pos] = s;
        coef[pos] = dinv[s] * dinv[d];
    }
}

// ---------------- GEMM: [nrows,128] @ [128,128] -> bf16 [nrows,128] ----------------

__global__ void gemm128(const float* __restrict__ X, const float* __restrict__ W,
                        u16* __restrict__ Hb, int nrows) {
    __shared__ float As[64][33];
    __shared__ float Bs[32][129];
    int block_row = blockIdx.x * 64;
    int tid = threadIdx.x;
    int tx = tid & 15;
    int ty = tid >> 4;
    float acc[4][8];
    #pragma unroll
    for (int i = 0; i < 4; i++)
        #pragma unroll
        for (int j = 0; j < 8; j++) acc[i][j] = 0.f;

    for (int k0 = 0; k0 < 128; k0 += 32) {
        #pragma unroll
        for (int l = tid; l < 512; l += 256) {
            int r = l >> 3, c4 = l & 7;
            int gr = block_row + r;
            float4 v = make_float4(0.f, 0.f, 0.f, 0.f);
            if (gr < nrows) v = *(const float4*)&X[(size_t)gr * 128 + k0 + c4 * 4];
            As[r][c4 * 4 + 0] = v.x; As[r][c4 * 4 + 1] = v.y;
            As[r][c4 * 4 + 2] = v.z; As[r][c4 * 4 + 3] = v.w;
        }
        #pragma unroll
        for (int l = tid; l < 1024; l += 256) {
            int r = l >> 5, c4 = l & 31;
            float4 v = *(const float4*)&W[(size_t)(k0 + r) * 128 + c4 * 4];
            Bs[r][c4 * 4 + 0] = v.x; Bs[r][c4 * 4 + 1] = v.y;
            Bs[r][c4 * 4 + 2] = v.z; Bs[r][c4 * 4 + 3] = v.w;
        }
        __syncthreads();
        #pragma unroll
        for (int kk = 0; kk < 32; kk++) {
            float a[4], b[8];
            #pragma unroll
            for (int i = 0; i < 4; i++) a[i] = As[ty * 4 + i][kk];
            #pragma unroll
            for (int j = 0; j < 8; j++) b[j] = Bs[kk][tx * 8 + j];
            #pragma unroll
            for (int i = 0; i < 4; i++)
                #pragma unroll
                for (int j = 0; j < 8; j++) acc[i][j] += a[i] * b[j];
        }
        __syncthreads();
    }
    #pragma unroll
    for (int i = 0; i < 4; i++) {
        int gr = block_row + ty * 4 + i;
        if (gr < nrows) {
            uint4 p;
            p.x = packbf2(acc[i][0], acc[i][1]);
            p.y = packbf2(acc[i][2], acc[i][3]);
            p.z = packbf2(acc[i][4], acc[i][5]);
            p.w = packbf2(acc[i][6], acc[i][7]);
            *(uint4*)&Hb[(size_t)gr * 128 + tx * 8] = p;
        }
    }
}

// ---------------- GEMM3: [nrows,128] @ [128,40] -> bf16 [nrows,40] ----------------
// one wave per row; LDS W padded so lanes 40..63 read garbage safely.

__global__ void gemm40(const float* __restrict__ H, const float* __restrict__ W3,
                       u16* __restrict__ Ob, int nrows) {
    __shared__ float Ws[128 * N_CLASSES + 64];
    for (int l = threadIdx.x; l < 128 * N_CLASSES + 64; l += blockDim.x)
        Ws[l] = (l < 128 * N_CLASSES) ? W3[l] : 0.f;
    __syncthreads();
    int wave = threadIdx.x >> 6;
    int lane = threadIdx.x & 63;
    int row = blockIdx.x * (blockDim.x >> 6) + wave;
    if (row >= nrows) return;
    const float* hrow = &H[(size_t)row * 128];
    float acc = 0.f;
    #pragma unroll 8
    for (int k = 0; k < 128; k++) acc += hrow[k] * Ws[k * N_CLASSES + lane];
    if (lane < N_CLASSES) Ob[(size_t)row * N_CLASSES + lane] = (u16)f2bf(acc);
}

// ---------------- Aggregation (128-wide, bf16 gather): pull + self-loop + bias + relu ----

__global__ void agg128_bf16(const u16* __restrict__ Hb, const int* __restrict__ rowptr,
                            const int* __restrict__ colidx, const float* __restrict__ coef,
                            const float* __restrict__ dinv, const float* __restrict__ bias,
                            float* __restrict__ O, int nrows) {
    int wave = threadIdx.x >> 6;
    int lane = threadIdx.x & 63;
    int node = blockIdx.x * (blockDim.x >> 6) + wave;
    if (node >= nrows) return;
    const u32* H32 = (const u32*)Hb;   // 2 bf16 per u32; row stride = 64 u32
    int beg = rowptr[node], end = rowptr[node + 1];
    float di = dinv[node];
    float cs = di * di;
    u32 hv = H32[(size_t)node * 64 + lane];
    float ax = cs * bflo(hv), ay = cs * bfhi(hv);
    int j = beg;
    for (; j + 4 <= end; j += 4) {
        int s0 = colidx[j], s1 = colidx[j + 1], s2 = colidx[j + 2], s3 = colidx[j + 3];
        float c0 = coef[j], c1 = coef[j + 1], c2 = coef[j + 2], c3 = coef[j + 3];
        u32 v0 = H32[(size_t)s0 * 64 + lane];
        u32 v1 = H32[(size_t)s1 * 64 + lane];
        u32 v2 = H32[(size_t)s2 * 64 + lane];
        u32 v3 = H32[(size_t)s3 * 64 + lane];
        ax += c0 * bflo(v0); ay += c0 * bfhi(v0);
        ax += c1 * bflo(v1); ay += c1 * bfhi(v1);
        ax += c2 * bflo(v2); ay += c2 * bfhi(v2);
        ax += c3 * bflo(v3); ay += c3 * bfhi(v3);
    }
    for (; j < end; j++) {
        int s = colidx[j];
        float c = coef[j];
        u32 v = H32[(size_t)s * 64 + lane];
        ax += c * bflo(v); ay += c * bfhi(v);
    }
    float2 b = ((const float2*)bias)[lane];
    ax = fmaxf(ax + b.x, 0.f);
    ay = fmaxf(ay + b.y, 0.f);
    float2 r; r.x = ax; r.y = ay;
    ((float2*)&O[(size_t)node * 128])[lane] = r;
}

// ---------------- Aggregation (40-wide bf16) + bias + log_softmax ----------------
// Hb is padded by >=64 u16 past the end so lanes 40..63 can load garbage safely.

__global__ void agg40_lsm(const u16* __restrict__ Hb, const int* __restrict__ rowptr,
                          const int* __restrict__ colidx, const float* __restrict__ coef,
                          const float* __restrict__ dinv, const float* __restrict__ bias,
                          float* __restrict__ out, int nrows) {
    int wave = threadIdx.x >> 6;
    int lane = threadIdx.x & 63;
    int node = blockIdx.x * (blockDim.x >> 6) + wave;
    if (node >= nrows) return;
    int beg = rowptr[node], end = rowptr[node + 1];
    float di = dinv[node];
    float acc = di * di * bf1(Hb[(size_t)node * N_CLASSES + lane]);
    int j = beg;
    for (; j + 4 <= end; j += 4) {
        int s0 = colidx[j], s1 = colidx[j + 1], s2 = colidx[j + 2], s3 = colidx[j + 3];
        float c0 = coef[j], c1 = coef[j + 1], c2 = coef[j + 2], c3 = coef[j + 3];
        float v0 = bf1(Hb[(size_t)s0 * N_CLASSES + lane]);
        float v1 = bf1(Hb[(size_t)s1 * N_CLASSES + lane]);
        float v2 = bf1(Hb[(size_t)s2 * N_CLASSES + lane]);
        float v3 = bf1(Hb[(size_t)s3 * N_CLASSES + lane]);
        acc += c0 * v0 + c1 * v1 + c2 * v2 + c3 * v3;
    }
    for (; j < end; j++) {
        acc += coef[j] * bf1(Hb[(size_t)colidx[j] * N_CLASSES + lane]);
    }
    if (lane < N_CLASSES) acc += bias[lane];
    float m = (lane < N_CLASSES) ? acc : -INFINITY;
    #pragma unroll
    for (int off = 32; off > 0; off >>= 1) m = fmaxf(m, __shfl_xor(m, off));
    float e = (lane < N_CLASSES) ? expf(acc - m) : 0.f;
    #pragma unroll
    for (int off = 32; off > 0; off >>= 1) e += __shfl_xor(e, off);
    float ls = logf(e);
    if (lane < N_CLASSES) out[(size_t)node * N_CLASSES + lane] = acc - m - ls;
}

// ---------------- launch ----------------

extern "C" void kernel_launch(void* const* d_in, const int* in_sizes, int n_in,
                              void* d_out, int out_size, void* d_ws, size_t ws_size,
                              hipStream_t stream) {
    const float* x  = (const float*)d_in[0];
    const int*   ei = (const int*)d_in[1];
    const float* W1 = (const float*)d_in[2];
    const float* b1 = (const float*)d_in[3];
    const float* W2 = (const float*)d_in[4];
    const float* b2 = (const float*)d_in[5];
    const float* W3 = (const float*)d_in[6];
    const float* b3 = (const float*)d_in[7];
    float* out = (float*)d_out;

    int N = in_sizes[0] / N_FEAT;
    int E = in_sizes[1] / 2;
    const int* src = ei;
    const int* dst = ei + E;

    char* ws = (char*)d_ws;
    size_t off = 0;
    auto alloc = [&](size_t bytes) -> char* {
        char* p = ws + off;
        off = (off + bytes + 255) & ~(size_t)255;
        return p;
    };
    int*   deg_cnt = (int*)  alloc((size_t)N * 4);
    int*   counter = (int*)  alloc((size_t)N * 4);
    float* dinv    = (float*)alloc((size_t)N * 4);
    int*   rowptr  = (int*)  alloc((size_t)(N + 1) * 4);
    int*   colidx  = (int*)  alloc((size_t)E * 4);
    float* coef    = (float*)alloc((size_t)E * 4);
    u16*   Hb      = (u16*)  alloc((size_t)N * 128 * 2);          // bf16 GEMM out (gather source)
    float* A       = (float*)alloc((size_t)N * 128 * 4);          // fp32 agg out (GEMM input)
    u16*   Hb3     = (u16*)  alloc(((size_t)N * N_CLASSES + 64) * 2); // bf16 logits (+pad)

    int tpb = 256;
    int gN = (N + tpb - 1) / tpb;
    int gE = (E + tpb - 1) / tpb;

    // CSR build
    zero_i32<<<gN, tpb, 0, stream>>>(deg_cnt, N);
    zero_i32<<<gN, tpb, 0, stream>>>(counter, N);
    hist_kernel<<<gE, tpb, 0, stream>>>(dst, deg_cnt, E);
    dinv_kernel<<<gN, tpb, 0, stream>>>(deg_cnt, dinv, N);
    scan_kernel<<<1, 1024, 0, stream>>>(deg_cnt, rowptr, N);
    fill_kernel<<<gE, tpb, 0, stream>>>(src, dst, rowptr, counter, dinv, colidx, coef, E);

    int gGemm = (N + 63) / 64;
    int gAgg  = (N + 3) / 4;   // 4 waves/block, 1 node/wave

    // layer 1
    gemm128<<<gGemm, 256, 0, stream>>>(x, W1, Hb, N);
    agg128_bf16<<<gAgg, 256, 0, stream>>>(Hb, rowptr, colidx, coef, dinv, b1, A, N);
    // layer 2
    gemm128<<<gGemm, 256, 0, stream>>>(A, W2, Hb, N);
    agg128_bf16<<<gAgg, 256, 0, stream>>>(Hb, rowptr, colidx, coef, dinv, b2, A, N);
    // layer 3
    gemm40<<<gAgg, 256, 0, stream>>>(A, W3, Hb3, N);
    agg40_lsm<<<gAgg, 256, 0, stream>>>(Hb3, rowptr, colidx, coef, dinv, b3, out, N);
}

// Round 4
// 860.870 us; speedup vs baseline: 1.4810x; 1.1547x over previous
//
#include <hip/hip_runtime.h>
#include <math.h>

#define N_FEAT 128
#define N_CLASSES 40

typedef unsigned short u16;
typedef unsigned int u32;

// ---- bf16 helpers (manual RNE pack, cheap unpack) ----
__device__ __forceinline__ u32 f2bf(float f) {
    u32 u = __float_as_uint(f);
    return (u + 0x7fffu + ((u >> 16) & 1u)) >> 16;
}
__device__ __forceinline__ u32 packbf2(float lo, float hi) {
    return f2bf(lo) | (f2bf(hi) << 16);
}
__device__ __forceinline__ float bflo(u32 v) { return __uint_as_float(v << 16); }
__device__ __forceinline__ float bfhi(u32 v) { return __uint_as_float(v & 0xffff0000u); }
__device__ __forceinline__ float bf1(u16 v) { return __uint_as_float(((u32)v) << 16); }

// ---------------- CSR build ----------------

__global__ void zero_i32(int* __restrict__ p, int n) {
    int i = blockIdx.x * blockDim.x + threadIdx.x;
    if (i < n) p[i] = 0;
}

__global__ void hist_kernel(const int* __restrict__ dst, int* __restrict__ cnt, int E) {
    int e = blockIdx.x * blockDim.x + threadIdx.x;
    if (e < E) atomicAdd(&cnt[dst[e]], 1);
}

__global__ void dinv_kernel(const int* __restrict__ cnt, float* __restrict__ dinv, int n) {
    int i = blockIdx.x * blockDim.x + threadIdx.x;
    if (i < n) dinv[i] = rsqrtf((float)(cnt[i] + 1));   // +1 = self-loop
}

// --- hierarchical scan: scan1 (per-block 1024-elem scan) -> scan2 (block sums) -> scan3 (add) ---

__global__ void scan1_kernel(const int* __restrict__ cnt, int* __restrict__ rowptr,
                             int* __restrict__ bsum, int n) {
    __shared__ int part[256];
    int b = blockIdx.x;
    int t = threadIdx.x;
    int base = b * 1024 + t * 4;
    int v0 = 0, v1 = 0, v2 = 0, v3 = 0;
    if (base + 3 < n) {
        int4 v = *(const int4*)&cnt[base];
        v0 = v.x; v1 = v.y; v2 = v.z; v3 = v.w;
    } else {
        if (base + 0 < n) v0 = cnt[base + 0];
        if (base + 1 < n) v1 = cnt[base + 1];
        if (base + 2 < n) v2 = cnt[base + 2];
        if (base + 3 < n) v3 = cnt[base + 3];
    }
    int s = v0 + v1 + v2 + v3;
    part[t] = s;
    __syncthreads();
    #pragma unroll
    for (int off = 1; off < 256; off <<= 1) {
        int mine = part[t];
        int other = (t >= off) ? part[t - off] : 0;
        __syncthreads();
        part[t] = mine + other;
        __syncthreads();
    }
    int excl = part[t] - s;
    if (base + 0 < n) rowptr[base + 0] = excl;
    if (base + 1 < n) rowptr[base + 1] = excl + v0;
    if (base + 2 < n) rowptr[base + 2] = excl + v0 + v1;
    if (base + 3 < n) rowptr[base + 3] = excl + v0 + v1 + v2;
    if (t == 255) bsum[b] = part[255];
}

// single block, 1024 threads: exclusive scan of nb block sums; writes rowptr[n]=total
__global__ void scan2_kernel(const int* __restrict__ bsum, int* __restrict__ boff,
                             int* __restrict__ rowptr, int nb, int n) {
    __shared__ int part[1024];
    int t = threadIdx.x;
    int s = (t < nb) ? bsum[t] : 0;
    part[t] = s;
    __syncthreads();
    for (int off = 1; off < 1024; off <<= 1) {
        int mine = part[t];
        int other = (t >= off) ? part[t - off] : 0;
        __syncthreads();
        part[t] = mine + other;
        __syncthreads();
    }
    if (t < nb) boff[t] = part[t] - s;
    if (t == 1023) rowptr[n] = part[1023];
}

__global__ void scan3_kernel(int* __restrict__ rowptr, const int* __restrict__ boff, int n) {
    int i = blockIdx.x * blockDim.x + threadIdx.x;
    if (i < n) rowptr[i] += boff[i >> 10];
}

__global__ void fill_kernel(const int* __restrict__ src, const int* __restrict__ dst,
                            const int* __restrict__ rowptr, int* __restrict__ counter,
                            const float* __restrict__ dinv,
                            int* __restrict__ colidx, float* __restrict__ coef, int E) {
    int e = blockIdx.x * blockDim.x + threadIdx.x;
    if (e < E) {
        int d = dst[e], s = src[e];
        int pos = rowptr[d] + atomicAdd(&counter[d], 1);
        colidx[pos] = s;
        coef[pos] = dinv[s] * dinv[d];
    }
}

// ---------------- GEMM: [nrows,128] @ [128,128] -> bf16 [nrows,128] ----------------

__global__ void gemm128(const float* __restrict__ X, const float* __restrict__ W,
                        u16* __restrict__ Hb, int nrows) {
    __shared__ float As[64][33];
    __shared__ float Bs[32][129];
    int block_row = blockIdx.x * 64;
    int tid = threadIdx.x;
    int tx = tid & 15;
    int ty = tid >> 4;
    float acc[4][8];
    #pragma unroll
    for (int i = 0; i < 4; i++)
        #pragma unroll
        for (int j = 0; j < 8; j++) acc[i][j] = 0.f;

    for (int k0 = 0; k0 < 128; k0 += 32) {
        #pragma unroll
        for (int l = tid; l < 512; l += 256) {
            int r = l >> 3, c4 = l & 7;
            int gr = block_row + r;
            float4 v = make_float4(0.f, 0.f, 0.f, 0.f);
            if (gr < nrows) v = *(const float4*)&X[(size_t)gr * 128 + k0 + c4 * 4];
            As[r][c4 * 4 + 0] = v.x; As[r][c4 * 4 + 1] = v.y;
            As[r][c4 * 4 + 2] = v.z; As[r][c4 * 4 + 3] = v.w;
        }
        #pragma unroll
        for (int l = tid; l < 1024; l += 256) {
            int r = l >> 5, c4 = l & 31;
            float4 v = *(const float4*)&W[(size_t)(k0 + r) * 128 + c4 * 4];
            Bs[r][c4 * 4 + 0] = v.x; Bs[r][c4 * 4 + 1] = v.y;
            Bs[r][c4 * 4 + 2] = v.z; Bs[r][c4 * 4 + 3] = v.w;
        }
        __syncthreads();
        #pragma unroll
        for (int kk = 0; kk < 32; kk++) {
            float a[4], b[8];
            #pragma unroll
            for (int i = 0; i < 4; i++) a[i] = As[ty * 4 + i][kk];
            #pragma unroll
            for (int j = 0; j < 8; j++) b[j] = Bs[kk][tx * 8 + j];
            #pragma unroll
            for (int i = 0; i < 4; i++)
                #pragma unroll
                for (int j = 0; j < 8; j++) acc[i][j] += a[i] * b[j];
        }
        __syncthreads();
    }
    #pragma unroll
    for (int i = 0; i < 4; i++) {
        int gr = block_row + ty * 4 + i;
        if (gr < nrows) {
            uint4 p;
            p.x = packbf2(acc[i][0], acc[i][1]);
            p.y = packbf2(acc[i][2], acc[i][3]);
            p.z = packbf2(acc[i][4], acc[i][5]);
            p.w = packbf2(acc[i][6], acc[i][7]);
            *(uint4*)&Hb[(size_t)gr * 128 + tx * 8] = p;
        }
    }
}

// ---------------- GEMM3: [nrows,128] @ [128,40] -> bf16 [nrows,40] ----------------

__global__ void gemm40(const float* __restrict__ H, const float* __restrict__ W3,
                       u16* __restrict__ Ob, int nrows) {
    __shared__ float Ws[128 * N_CLASSES + 64];
    for (int l = threadIdx.x; l < 128 * N_CLASSES + 64; l += blockDim.x)
        Ws[l] = (l < 128 * N_CLASSES) ? W3[l] : 0.f;
    __syncthreads();
    int wave = threadIdx.x >> 6;
    int lane = threadIdx.x & 63;
    int row = blockIdx.x * (blockDim.x >> 6) + wave;
    if (row >= nrows) return;
    const float* hrow = &H[(size_t)row * 128];
    float acc = 0.f;
    #pragma unroll 8
    for (int k = 0; k < 128; k++) acc += hrow[k] * Ws[k * N_CLASSES + lane];
    if (lane < N_CLASSES) Ob[(size_t)row * N_CLASSES + lane] = (u16)f2bf(acc);
}

// ---------------- Aggregation (128-wide, bf16 gather): pull + self-loop + bias + relu ----

__global__ void agg128_bf16(const u16* __restrict__ Hb, const int* __restrict__ rowptr,
                            const int* __restrict__ colidx, const float* __restrict__ coef,
                            const float* __restrict__ dinv, const float* __restrict__ bias,
                            float* __restrict__ O, int nrows) {
    int wave = threadIdx.x >> 6;
    int lane = threadIdx.x & 63;
    int node = blockIdx.x * (blockDim.x >> 6) + wave;
    if (node >= nrows) return;
    const u32* H32 = (const u32*)Hb;   // 2 bf16 per u32; row stride = 64 u32
    int beg = rowptr[node], end = rowptr[node + 1];
    float di = dinv[node];
    float cs = di * di;
    u32 hv = H32[(size_t)node * 64 + lane];
    float ax = cs * bflo(hv), ay = cs * bfhi(hv);
    int j = beg;
    for (; j + 4 <= end; j += 4) {
        int s0 = colidx[j], s1 = colidx[j + 1], s2 = colidx[j + 2], s3 = colidx[j + 3];
        float c0 = coef[j], c1 = coef[j + 1], c2 = coef[j + 2], c3 = coef[j + 3];
        u32 v0 = H32[(size_t)s0 * 64 + lane];
        u32 v1 = H32[(size_t)s1 * 64 + lane];
        u32 v2 = H32[(size_t)s2 * 64 + lane];
        u32 v3 = H32[(size_t)s3 * 64 + lane];
        ax += c0 * bflo(v0); ay += c0 * bfhi(v0);
        ax += c1 * bflo(v1); ay += c1 * bfhi(v1);
        ax += c2 * bflo(v2); ay += c2 * bfhi(v2);
        ax += c3 * bflo(v3); ay += c3 * bfhi(v3);
    }
    for (; j < end; j++) {
        int s = colidx[j];
        float c = coef[j];
        u32 v = H32[(size_t)s * 64 + lane];
        ax += c * bflo(v); ay += c * bfhi(v);
    }
    float2 b = ((const float2*)bias)[lane];
    ax = fmaxf(ax + b.x, 0.f);
    ay = fmaxf(ay + b.y, 0.f);
    float2 r; r.x = ax; r.y = ay;
    ((float2*)&O[(size_t)node * 128])[lane] = r;
}

// ---------------- Aggregation (40-wide bf16) + bias + log_softmax ----------------

__global__ void agg40_lsm(const u16* __restrict__ Hb, const int* __restrict__ rowptr,
                          const int* __restrict__ colidx, const float* __restrict__ coef,
                          const float* __restrict__ dinv, const float* __restrict__ bias,
                          float* __restrict__ out, int nrows) {
    int wave = threadIdx.x >> 6;
    int lane = threadIdx.x & 63;
    int node = blockIdx.x * (blockDim.x >> 6) + wave;
    if (node >= nrows) return;
    int beg = rowptr[node], end = rowptr[node + 1];
    float di = dinv[node];
    float acc = di * di * bf1(Hb[(size_t)node * N_CLASSES + lane]);
    int j = beg;
    for (; j + 4 <= end; j += 4) {
        int s0 = colidx[j], s1 = colidx[j + 1], s2 = colidx[j + 2], s3 = colidx[j + 3];
        float c0 = coef[j], c1 = coef[j + 1], c2 = coef[j + 2], c3 = coef[j + 3];
        float v0 = bf1(Hb[(size_t)s0 * N_CLASSES + lane]);
        float v1 = bf1(Hb[(size_t)s1 * N_CLASSES + lane]);
        float v2 = bf1(Hb[(size_t)s2 * N_CLASSES + lane]);
        float v3 = bf1(Hb[(size_t)s3 * N_CLASSES + lane]);
        acc += c0 * v0 + c1 * v1 + c2 * v2 + c3 * v3;
    }
    for (; j < end; j++) {
        acc += coef[j] * bf1(Hb[(size_t)colidx[j] * N_CLASSES + lane]);
    }
    if (lane < N_CLASSES) acc += bias[lane];
    float m = (lane < N_CLASSES) ? acc : -INFINITY;
    #pragma unroll
    for (int off = 32; off > 0; off >>= 1) m = fmaxf(m, __shfl_xor(m, off));
    float e = (lane < N_CLASSES) ? expf(acc - m) : 0.f;
    #pragma unroll
    for (int off = 32; off > 0; off >>= 1) e += __shfl_xor(e, off);
    float ls = logf(e);
    if (lane < N_CLASSES) out[(size_t)node * N_CLASSES + lane] = acc - m - ls;
}

// ---------------- launch ----------------

extern "C" void kernel_launch(void* const* d_in, const int* in_sizes, int n_in,
                              void* d_out, int out_size, void* d_ws, size_t ws_size,
                              hipStream_t stream) {
    const float* x  = (const float*)d_in[0];
    const int*   ei = (const int*)d_in[1];
    const float* W1 = (const float*)d_in[2];
    const float* b1 = (const float*)d_in[3];
    const float* W2 = (const float*)d_in[4];
    const float* b2 = (const float*)d_in[5];
    const float* W3 = (const float*)d_in[6];
    const float* b3 = (const float*)d_in[7];
    float* out = (float*)d_out;

    int N = in_sizes[0] / N_FEAT;
    int E = in_sizes[1] / 2;
    const int* src = ei;
    const int* dst = ei + E;

    char* ws = (char*)d_ws;
    size_t off = 0;
    auto alloc = [&](size_t bytes) -> char* {
        char* p = ws + off;
        off = (off + bytes + 255) & ~(size_t)255;
        return p;
    };
    int*   deg_cnt = (int*)  alloc((size_t)N * 4);
    int*   counter = (int*)  alloc((size_t)N * 4);
    float* dinv    = (float*)alloc((size_t)N * 4);
    int*   rowptr  = (int*)  alloc((size_t)(N + 1) * 4);
    int*   colidx  = (int*)  alloc((size_t)E * 4);
    float* coef    = (float*)alloc((size_t)E * 4);
    int*   bsum    = (int*)  alloc((size_t)1024 * 4);
    int*   boff    = (int*)  alloc((size_t)1024 * 4);
    u16*   Hb      = (u16*)  alloc((size_t)N * 128 * 2);
    float* A       = (float*)alloc((size_t)N * 128 * 4);
    u16*   Hb3     = (u16*)  alloc(((size_t)N * N_CLASSES + 64) * 2);

    int tpb = 256;
    int gN = (N + tpb - 1) / tpb;
    int gE = (E + tpb - 1) / tpb;
    int nb = (N + 1023) / 1024;   // scan blocks

    // Zero deg_cnt AND counter in one launch. NOTE: alloc() pads to 256 B, so
    // counter != deg_cnt + N. Span computed from actual pointers (includes pad).
    int zspan = (int)(counter - deg_cnt) + N;
    zero_i32<<<(zspan + tpb - 1) / tpb, tpb, 0, stream>>>(deg_cnt, zspan);
    hist_kernel<<<gE, tpb, 0, stream>>>(dst, deg_cnt, E);
    dinv_kernel<<<gN, tpb, 0, stream>>>(deg_cnt, dinv, N);
    scan1_kernel<<<nb, 256, 0, stream>>>(deg_cnt, rowptr, bsum, N);
    scan2_kernel<<<1, 1024, 0, stream>>>(bsum, boff, rowptr, nb, N);
    scan3_kernel<<<gN, tpb, 0, stream>>>(rowptr, boff, N);
    fill_kernel<<<gE, tpb, 0, stream>>>(src, dst, rowptr, counter, dinv, colidx, coef, E);

    int gGemm = (N + 63) / 64;
    int gAgg  = (N + 3) / 4;   // 4 waves/block, 1 node/wave

    // layer 1
    gemm128<<<gGemm, 256, 0, stream>>>(x, W1, Hb, N);
    agg128_bf16<<<gAgg, 256, 0, stream>>>(Hb, rowptr, colidx, coef, dinv, b1, A, N);
    // layer 2
    gemm128<<<gGemm, 256, 0, stream>>>(A, W2, Hb, N);
    agg128_bf16<<<gAgg, 256, 0, stream>>>(Hb, rowptr, colidx, coef, dinv, b2, A, N);
    // layer 3
    gemm40<<<gAgg, 256, 0, stream>>>(A, W3, Hb3, N);
    agg40_lsm<<<gAgg, 256, 0, stream>>>(Hb3, rowptr, colidx, coef, dinv, b3, out, N);
}

// Round 5
// 537.581 us; speedup vs baseline: 2.3716x; 1.6014x over previous
//
#include <hip/hip_runtime.h>
#include <math.h>

#define N_FEAT 128
#define N_CLASSES 40

typedef unsigned short u16;
typedef unsigned int u32;
typedef short bf16x8 __attribute__((ext_vector_type(8)));
typedef float f32x4 __attribute__((ext_vector_type(4)));

// ---- bf16 helpers (manual RNE pack, cheap unpack) ----
__device__ __forceinline__ u32 f2bf(float f) {
    u32 u = __float_as_uint(f);
    return (u + 0x7fffu + ((u >> 16) & 1u)) >> 16;
}
__device__ __forceinline__ u32 packbf2(float lo, float hi) {
    return f2bf(lo) | (f2bf(hi) << 16);
}
__device__ __forceinline__ float bflo(u32 v) { return __uint_as_float(v << 16); }
__device__ __forceinline__ float bfhi(u32 v) { return __uint_as_float(v & 0xffff0000u); }

// ---------------- CSR build ----------------

__global__ void zero_i32(int* __restrict__ p, int n) {
    int i = blockIdx.x * blockDim.x + threadIdx.x;
    if (i < n) p[i] = 0;
}

__global__ void hist_kernel(const int* __restrict__ dst, int* __restrict__ cnt, int E) {
    int e = blockIdx.x * blockDim.x + threadIdx.x;
    if (e < E) atomicAdd(&cnt[dst[e]], 1);
}

__global__ void dinv_kernel(const int* __restrict__ cnt, float* __restrict__ dinv, int n) {
    int i = blockIdx.x * blockDim.x + threadIdx.x;
    if (i < n) dinv[i] = rsqrtf((float)(cnt[i] + 1));   // +1 = self-loop
}

__global__ void scan1_kernel(const int* __restrict__ cnt, int* __restrict__ rowptr,
                             int* __restrict__ bsum, int n) {
    __shared__ int part[256];
    int b = blockIdx.x;
    int t = threadIdx.x;
    int base = b * 1024 + t * 4;
    int v0 = 0, v1 = 0, v2 = 0, v3 = 0;
    if (base + 3 < n) {
        int4 v = *(const int4*)&cnt[base];
        v0 = v.x; v1 = v.y; v2 = v.z; v3 = v.w;
    } else {
        if (base + 0 < n) v0 = cnt[base + 0];
        if (base + 1 < n) v1 = cnt[base + 1];
        if (base + 2 < n) v2 = cnt[base + 2];
        if (base + 3 < n) v3 = cnt[base + 3];
    }
    int s = v0 + v1 + v2 + v3;
    part[t] = s;
    __syncthreads();
    #pragma unroll
    for (int off = 1; off < 256; off <<= 1) {
        int mine = part[t];
        int other = (t >= off) ? part[t - off] : 0;
        __syncthreads();
        part[t] = mine + other;
        __syncthreads();
    }
    int excl = part[t] - s;
    if (base + 0 < n) rowptr[base + 0] = excl;
    if (base + 1 < n) rowptr[base + 1] = excl + v0;
    if (base + 2 < n) rowptr[base + 2] = excl + v0 + v1;
    if (base + 3 < n) rowptr[base + 3] = excl + v0 + v1 + v2;
    if (t == 255) bsum[b] = part[255];
}

__global__ void scan2_kernel(const int* __restrict__ bsum, int* __restrict__ boff,
                             int* __restrict__ rowptr, int nb, int n) {
    __shared__ int part[1024];
    int t = threadIdx.x;
    int s = (t < nb) ? bsum[t] : 0;
    part[t] = s;
    __syncthreads();
    for (int off = 1; off < 1024; off <<= 1) {
        int mine = part[t];
        int other = (t >= off) ? part[t - off] : 0;
        __syncthreads();
        part[t] = mine + other;
        __syncthreads();
    }
    if (t < nb) boff[t] = part[t] - s;
    if (t == 1023) rowptr[n] = part[1023];
}

__global__ void scan3_kernel(int* __restrict__ rowptr, const int* __restrict__ boff, int n) {
    int i = blockIdx.x * blockDim.x + threadIdx.x;
    if (i < n) rowptr[i] += boff[i >> 10];
}

__global__ void fill_kernel(const int* __restrict__ src, const int* __restrict__ dst,
                            const int* __restrict__ rowptr, int* __restrict__ counter,
                            const float* __restrict__ dinv,
                            int* __restrict__ colidx, float* __restrict__ coef, int E) {
    int e = blockIdx.x * blockDim.x + threadIdx.x;
    if (e < E) {
        int d = dst[e], s = src[e];
        int pos = rowptr[d] + atomicAdd(&counter[d], 1);
        colidx[pos] = s;
        coef[pos] = dinv[s] * dinv[d];
    }
}

// ---------------- dtype conversions ----------------

__global__ void f32_to_bf16_vec(const float* __restrict__ in, u16* __restrict__ outb, int n4) {
    int i = blockIdx.x * blockDim.x + threadIdx.x;   // 4 floats per thread
    if (i < n4) {
        float4 v = ((const float4*)in)[i];
        uint2 p; p.x = packbf2(v.x, v.y); p.y = packbf2(v.z, v.w);
        ((uint2*)outb)[i] = p;
    }
}

// W [128][128] fp32 -> Wt [n=128][k=128] bf16 (transposed)
__global__ void cvt_w_t(const float* __restrict__ W, u16* __restrict__ Wt) {
    int i = blockIdx.x * blockDim.x + threadIdx.x;   // 16384 threads
    int n = i & 127, k = i >> 7;
    Wt[(size_t)n * 128 + k] = (u16)f2bf(W[(size_t)k * 128 + n]);
}

// W3 [128][40] fp32 -> W3t [n=48][k=128] bf16 (transposed, zero-padded cols 40..47)
__global__ void cvt_w3_t(const float* __restrict__ W3, u16* __restrict__ W3t) {
    int i = blockIdx.x * blockDim.x + threadIdx.x;   // 48*128 = 6144 threads
    int k = i & 127, n = i >> 7;
    W3t[(size_t)n * 128 + k] = (n < N_CLASSES) ? (u16)f2bf(W3[(size_t)k * N_CLASSES + n]) : (u16)0;
}

// ---------------- MFMA GEMM: bf16 [N,128] @ bf16 Wt[128n][128k] -> bf16 [N,128] ----------------
// block 256 = 4 waves; 64 rows/block (16/wave); 8 n-tiles of 16; K-loop 4 x 32.
// LDS W padded to 136 bf16/row (68-dword stride -> 2-way bank alias = free).

__global__ __launch_bounds__(256) void gemm128_mfma(const u16* __restrict__ Ab,
                                                    const u16* __restrict__ Wt,
                                                    u16* __restrict__ Hb, int nrows) {
    __shared__ u16 Bs[128 * 136];
    int tid = threadIdx.x;
    #pragma unroll
    for (int i = 0; i < 8; i++) {
        int c = i * 256 + tid;          // 16B chunk id; 2048 chunks = 32 KB
        int n = c >> 4, cc = c & 15;    // 16 chunks per 256B source row
        *(uint4*)&Bs[n * 136 + cc * 8] = ((const uint4*)Wt)[c];
    }
    __syncthreads();
    int wave = tid >> 6, lane = tid & 63;
    int quad = lane >> 4, l16 = lane & 15;
    int rowbase = blockIdx.x * 64 + wave * 16;
    int arow = rowbase + l16; if (arow >= nrows) arow = nrows - 1;  // clamp (store guarded)
    const u16* aptr = Ab + (size_t)arow * 128 + quad * 8;
    f32x4 acc[8];
    #pragma unroll
    for (int t = 0; t < 8; t++) acc[t] = (f32x4){0.f, 0.f, 0.f, 0.f};
    #pragma unroll
    for (int kk = 0; kk < 4; kk++) {
        bf16x8 a = *(const bf16x8*)(aptr + kk * 32);
        #pragma unroll
        for (int t = 0; t < 8; t++) {
            bf16x8 b = *(const bf16x8*)&Bs[(size_t)(t * 16 + l16) * 136 + kk * 32 + quad * 8];
            acc[t] = __builtin_amdgcn_mfma_f32_16x16x32_bf16(a, b, acc[t], 0, 0, 0);
        }
    }
    #pragma unroll
    for (int r = 0; r < 4; r++) {
        int orow = rowbase + quad * 4 + r;
        if (orow < nrows) {
            #pragma unroll
            for (int t = 0; t < 8; t++)
                Hb[(size_t)orow * 128 + t * 16 + l16] = (u16)f2bf(acc[t][r]);
        }
    }
}

// ---------------- final: bf16 [N,128] @ W3t[48n][128k] + b3, log_softmax -> fp32 [N,40] ----------

__global__ __launch_bounds__(256) void gemm40_lsm(const u16* __restrict__ G,
                                                  const u16* __restrict__ W3t,
                                                  const float* __restrict__ b3,
                                                  float* __restrict__ out, int nrows) {
    __shared__ u16 Bs[48 * 136];
    __shared__ float Ls[4][16][48];
    int tid = threadIdx.x;
    for (int c = tid; c < 768; c += 256) {          // 48*128*2B = 768 16B chunks
        int n = c >> 4, cc = c & 15;
        *(uint4*)&Bs[n * 136 + cc * 8] = ((const uint4*)W3t)[c];
    }
    __syncthreads();
    int wave = tid >> 6, lane = tid & 63;
    int quad = lane >> 4, l16 = lane & 15;
    int rowbase = blockIdx.x * 64 + wave * 16;
    int arow = rowbase + l16; if (arow >= nrows) arow = nrows - 1;
    const u16* aptr = G + (size_t)arow * 128 + quad * 8;
    f32x4 acc[3];
    #pragma unroll
    for (int t = 0; t < 3; t++) acc[t] = (f32x4){0.f, 0.f, 0.f, 0.f};
    #pragma unroll
    for (int kk = 0; kk < 4; kk++) {
        bf16x8 a = *(const bf16x8*)(aptr + kk * 32);
        #pragma unroll
        for (int t = 0; t < 3; t++) {
            bf16x8 b = *(const bf16x8*)&Bs[(size_t)(t * 16 + l16) * 136 + kk * 32 + quad * 8];
            acc[t] = __builtin_amdgcn_mfma_f32_16x16x32_bf16(a, b, acc[t], 0, 0, 0);
        }
    }
    #pragma unroll
    for (int r = 0; r < 4; r++)
        #pragma unroll
        for (int t = 0; t < 3; t++)
            Ls[wave][quad * 4 + r][t * 16 + l16] = acc[t][r];
    __syncthreads();
    float bval = (lane < N_CLASSES) ? b3[lane] : 0.f;
    for (int r = 0; r < 16; r++) {
        int row = rowbase + r;
        float v = (lane < N_CLASSES) ? Ls[wave][r][lane] + bval : -INFINITY;
        float m = v;
        #pragma unroll
        for (int off = 32; off > 0; off >>= 1) m = fmaxf(m, __shfl_xor(m, off));
        float e = (lane < N_CLASSES) ? expf(v - m) : 0.f;
        #pragma unroll
        for (int off = 32; off > 0; off >>= 1) e += __shfl_xor(e, off);
        float ls = logf(e);
        if (lane < N_CLASSES && row < nrows)
            out[(size_t)row * N_CLASSES + lane] = v - m - ls;
    }
}

// ---------------- Aggregation (128-wide, bf16 in/out): pull + self-loop [+ bias + relu] ----

template <int BIAS_RELU>
__global__ void agg128_bf16(const u16* __restrict__ Hb, const int* __restrict__ rowptr,
                            const int* __restrict__ colidx, const float* __restrict__ coef,
                            const float* __restrict__ dinv, const float* __restrict__ bias,
                            u16* __restrict__ Ob, int nrows) {
    int wave = threadIdx.x >> 6;
    int lane = threadIdx.x & 63;
    int node = blockIdx.x * (blockDim.x >> 6) + wave;
    if (node >= nrows) return;
    const u32* H32 = (const u32*)Hb;   // 2 bf16 per u32; row stride = 64 u32
    int beg = rowptr[node], end = rowptr[node + 1];
    float di = dinv[node];
    float cs = di * di;
    u32 hv = H32[(size_t)node * 64 + lane];
    float ax = cs * bflo(hv), ay = cs * bfhi(hv);
    int j = beg;
    for (; j + 4 <= end; j += 4) {
        int s0 = colidx[j], s1 = colidx[j + 1], s2 = colidx[j + 2], s3 = colidx[j + 3];
        float c0 = coef[j], c1 = coef[j + 1], c2 = coef[j + 2], c3 = coef[j + 3];
        u32 v0 = H32[(size_t)s0 * 64 + lane];
        u32 v1 = H32[(size_t)s1 * 64 + lane];
        u32 v2 = H32[(size_t)s2 * 64 + lane];
        u32 v3 = H32[(size_t)s3 * 64 + lane];
        ax += c0 * bflo(v0); ay += c0 * bfhi(v0);
        ax += c1 * bflo(v1); ay += c1 * bfhi(v1);
        ax += c2 * bflo(v2); ay += c2 * bfhi(v2);
        ax += c3 * bflo(v3); ay += c3 * bfhi(v3);
    }
    for (; j < end; j++) {
        int s = colidx[j];
        float c = coef[j];
        u32 v = H32[(size_t)s * 64 + lane];
        ax += c * bflo(v); ay += c * bfhi(v);
    }
    if (BIAS_RELU) {
        float2 b = ((const float2*)bias)[lane];
        ax = fmaxf(ax + b.x, 0.f);
        ay = fmaxf(ay + b.y, 0.f);
    }
    ((u32*)Ob)[(size_t)node * 64 + lane] = packbf2(ax, ay);
}

// ---------------- launch ----------------

extern "C" void kernel_launch(void* const* d_in, const int* in_sizes, int n_in,
                              void* d_out, int out_size, void* d_ws, size_t ws_size,
                              hipStream_t stream) {
    const float* x  = (const float*)d_in[0];
    const int*   ei = (const int*)d_in[1];
    const float* W1 = (const float*)d_in[2];
    const float* b1 = (const float*)d_in[3];
    const float* W2 = (const float*)d_in[4];
    const float* b2 = (const float*)d_in[5];
    const float* W3 = (const float*)d_in[6];
    const float* b3 = (const float*)d_in[7];
    float* out = (float*)d_out;

    int N = in_sizes[0] / N_FEAT;
    int E = in_sizes[1] / 2;
    const int* src = ei;
    const int* dst = ei + E;

    char* ws = (char*)d_ws;
    size_t off = 0;
    auto alloc = [&](size_t bytes) -> char* {
        char* p = ws + off;
        off = (off + bytes + 255) & ~(size_t)255;
        return p;
    };
    int*   deg_cnt = (int*)  alloc((size_t)N * 4);
    int*   counter = (int*)  alloc((size_t)N * 4);
    float* dinv    = (float*)alloc((size_t)N * 4);
    int*   rowptr  = (int*)  alloc((size_t)(N + 1) * 4);
    int*   colidx  = (int*)  alloc((size_t)E * 4);
    float* coef    = (float*)alloc((size_t)E * 4);
    int*   bsum    = (int*)  alloc((size_t)1024 * 4);
    int*   boff    = (int*)  alloc((size_t)1024 * 4);
    u16*   W1t     = (u16*)  alloc((size_t)128 * 128 * 2);
    u16*   W2t     = (u16*)  alloc((size_t)128 * 128 * 2);
    u16*   W3t     = (u16*)  alloc((size_t)48 * 128 * 2);
    u16*   xb      = (u16*)  alloc((size_t)N * 128 * 2);   // bf16 x; later reused as A2
    u16*   Hbuf    = (u16*)  alloc((size_t)N * 128 * 2);   // gemm out / G
    u16*   Abuf    = (u16*)  alloc((size_t)N * 128 * 2);   // agg out

    int tpb = 256;
    int gN = (N + tpb - 1) / tpb;
    int gE = (E + tpb - 1) / tpb;
    int nb = (N + 1023) / 1024;

    // Zero deg_cnt AND counter in one launch (span from actual pointers incl. 256B pad).
    int zspan = (int)(counter - deg_cnt) + N;
    zero_i32<<<(zspan + tpb - 1) / tpb, tpb, 0, stream>>>(deg_cnt, zspan);
    hist_kernel<<<gE, tpb, 0, stream>>>(dst, deg_cnt, E);
    dinv_kernel<<<gN, tpb, 0, stream>>>(deg_cnt, dinv, N);
    scan1_kernel<<<nb, 256, 0, stream>>>(deg_cnt, rowptr, bsum, N);
    scan2_kernel<<<1, 1024, 0, stream>>>(bsum, boff, rowptr, nb, N);
    scan3_kernel<<<gN, tpb, 0, stream>>>(rowptr, boff, N);
    fill_kernel<<<gE, tpb, 0, stream>>>(src, dst, rowptr, counter, dinv, colidx, coef, E);

    // dtype prep
    int n4 = N * 128 / 4;
    f32_to_bf16_vec<<<(n4 + tpb - 1) / tpb, tpb, 0, stream>>>(x, xb, n4);
    cvt_w_t<<<64, 256, 0, stream>>>(W1, W1t);
    cvt_w_t<<<64, 256, 0, stream>>>(W2, W2t);
    cvt_w3_t<<<24, 256, 0, stream>>>(W3, W3t);

    int gGemm = (N + 63) / 64;
    int gAgg  = (N + 3) / 4;   // 4 waves/block, 1 node/wave

    // layer 1
    gemm128_mfma<<<gGemm, 256, 0, stream>>>(xb, W1t, Hbuf, N);
    agg128_bf16<1><<<gAgg, 256, 0, stream>>>(Hbuf, rowptr, colidx, coef, dinv, b1, Abuf, N);
    // layer 2 (A2 -> xb buffer, no longer needed)
    gemm128_mfma<<<gGemm, 256, 0, stream>>>(Abuf, W2t, Hbuf, N);
    agg128_bf16<1><<<gAgg, 256, 0, stream>>>(Hbuf, rowptr, colidx, coef, dinv, b2, xb, N);
    // layer 3 reordered by linearity: G = agg(A2); out = lsm(G @ W3 + b3)
    agg128_bf16<0><<<gAgg, 256, 0, stream>>>(xb, rowptr, colidx, coef, dinv, b3, Hbuf, N);
    gemm40_lsm<<<gGemm, 256, 0, stream>>>(Hbuf, W3t, b3, out, N);
}

// Round 6
// 534.336 us; speedup vs baseline: 2.3860x; 1.0061x over previous
//
#include <hip/hip_runtime.h>
#include <math.h>

#define N_FEAT 128
#define N_CLASSES 40

typedef unsigned short u16;
typedef unsigned int u32;
typedef short bf16x8 __attribute__((ext_vector_type(8)));
typedef float f32x4 __attribute__((ext_vector_type(4)));

// ---- bf16 helpers (manual RNE pack, cheap unpack) ----
__device__ __forceinline__ u32 f2bf(float f) {
    u32 u = __float_as_uint(f);
    return (u + 0x7fffu + ((u >> 16) & 1u)) >> 16;
}
__device__ __forceinline__ u32 packbf2(float lo, float hi) {
    return f2bf(lo) | (f2bf(hi) << 16);
}
__device__ __forceinline__ float bflo(u32 v) { return __uint_as_float(v << 16); }
__device__ __forceinline__ float bfhi(u32 v) { return __uint_as_float(v & 0xffff0000u); }

// ---------------- CSR build ----------------

__global__ void zero_i32(int* __restrict__ p, int n) {
    int i = blockIdx.x * blockDim.x + threadIdx.x;
    if (i < n) p[i] = 0;
}

__global__ void hist_kernel(const int* __restrict__ dst, int* __restrict__ cnt, int E) {
    int e = blockIdx.x * blockDim.x + threadIdx.x;
    if (e < E) atomicAdd(&cnt[dst[e]], 1);
}

// per-block scan of 1024 counts + dinv computation (fused; scan1 reads cnt anyway)
__global__ void scan1_kernel(const int* __restrict__ cnt, int* __restrict__ rowptr,
                             int* __restrict__ bsum, float* __restrict__ dinv, int n) {
    __shared__ int part[256];
    int b = blockIdx.x;
    int t = threadIdx.x;
    int base = b * 1024 + t * 4;
    int v0 = 0, v1 = 0, v2 = 0, v3 = 0;
    if (base + 3 < n) {
        int4 v = *(const int4*)&cnt[base];
        v0 = v.x; v1 = v.y; v2 = v.z; v3 = v.w;
    } else {
        if (base + 0 < n) v0 = cnt[base + 0];
        if (base + 1 < n) v1 = cnt[base + 1];
        if (base + 2 < n) v2 = cnt[base + 2];
        if (base + 3 < n) v3 = cnt[base + 3];
    }
    if (base + 0 < n) dinv[base + 0] = rsqrtf((float)(v0 + 1));
    if (base + 1 < n) dinv[base + 1] = rsqrtf((float)(v1 + 1));
    if (base + 2 < n) dinv[base + 2] = rsqrtf((float)(v2 + 1));
    if (base + 3 < n) dinv[base + 3] = rsqrtf((float)(v3 + 1));
    int s = v0 + v1 + v2 + v3;
    part[t] = s;
    __syncthreads();
    #pragma unroll
    for (int off = 1; off < 256; off <<= 1) {
        int mine = part[t];
        int other = (t >= off) ? part[t - off] : 0;
        __syncthreads();
        part[t] = mine + other;
        __syncthreads();
    }
    int excl = part[t] - s;
    if (base + 0 < n) rowptr[base + 0] = excl;
    if (base + 1 < n) rowptr[base + 1] = excl + v0;
    if (base + 2 < n) rowptr[base + 2] = excl + v0 + v1;
    if (base + 3 < n) rowptr[base + 3] = excl + v0 + v1 + v2;
    if (t == 255) bsum[b] = part[255];
}

__global__ void scan2_kernel(const int* __restrict__ bsum, int* __restrict__ boff,
                             int* __restrict__ rowptr, int nb, int n) {
    __shared__ int part[1024];
    int t = threadIdx.x;
    int s = (t < nb) ? bsum[t] : 0;
    part[t] = s;
    __syncthreads();
    for (int off = 1; off < 1024; off <<= 1) {
        int mine = part[t];
        int other = (t >= off) ? part[t - off] : 0;
        __syncthreads();
        part[t] = mine + other;
        __syncthreads();
    }
    if (t < nb) boff[t] = part[t] - s;
    if (t == 1023) rowptr[n] = part[1023];
}

__global__ void scan3_kernel(int* __restrict__ rowptr, const int* __restrict__ boff, int n) {
    int i = blockIdx.x * blockDim.x + threadIdx.x;
    if (i < n) rowptr[i] += boff[i >> 10];
}

// fill: ONLY colidx (4B/edge scatter). coef eliminated by factoring dinv[d] out of the sum.
__global__ void fill_kernel(const int* __restrict__ src, const int* __restrict__ dst,
                            const int* __restrict__ rowptr, int* __restrict__ counter,
                            int* __restrict__ colidx, int E) {
    int e = blockIdx.x * blockDim.x + threadIdx.x;
    if (e < E) {
        int d = dst[e];
        int pos = rowptr[d] + atomicAdd(&counter[d], 1);
        colidx[pos] = src[e];
    }
}

// ---------------- weight conversions (merged into one launch) ----------------
// W1,W2 [128k][128n] fp32 -> W1t,W2t [n][k] bf16; W3 [128k][40n] -> W3t [48n][128k] (padded).

__global__ void cvt_weights(const float* __restrict__ W1, const float* __restrict__ W2,
                            const float* __restrict__ W3,
                            u16* __restrict__ W1t, u16* __restrict__ W2t, u16* __restrict__ W3t) {
    int i = blockIdx.x * blockDim.x + threadIdx.x;   // 0 .. 38912
    if (i < 16384) {
        int n = i & 127, k = i >> 7;
        W1t[(size_t)n * 128 + k] = (u16)f2bf(W1[(size_t)k * 128 + n]);
    } else if (i < 32768) {
        int j = i - 16384;
        int n = j & 127, k = j >> 7;
        W2t[(size_t)n * 128 + k] = (u16)f2bf(W2[(size_t)k * 128 + n]);
    } else if (i < 32768 + 6144) {
        int j = i - 32768;
        int k = j & 127, n = j >> 7;
        W3t[(size_t)n * 128 + k] = (n < N_CLASSES) ? (u16)f2bf(W3[(size_t)k * N_CLASSES + n]) : (u16)0;
    }
}

// ---------------- MFMA GEMM: [N,128] @ Wt[128n][128k] -> bf16 [N,128] ----------------
// A dtype templated: fp32 (layer 1, packs in-register) or bf16.
// LDS W padded to 136 bf16/row (68-dword stride -> 2-way bank alias = free).

template <typename AT>
__device__ __forceinline__ bf16x8 load_a_frag(const AT* aptr);

template <>
__device__ __forceinline__ bf16x8 load_a_frag<u16>(const u16* aptr) {
    return *(const bf16x8*)aptr;
}
template <>
__device__ __forceinline__ bf16x8 load_a_frag<float>(const float* aptr) {
    float4 lo = *(const float4*)aptr;
    float4 hi = *(const float4*)(aptr + 4);
    union { u32 u[4]; bf16x8 v; } r;
    r.u[0] = packbf2(lo.x, lo.y);
    r.u[1] = packbf2(lo.z, lo.w);
    r.u[2] = packbf2(hi.x, hi.y);
    r.u[3] = packbf2(hi.z, hi.w);
    return r.v;
}

template <typename AT>
__global__ __launch_bounds__(256) void gemm128_mfma(const AT* __restrict__ Ab,
                                                    const u16* __restrict__ Wt,
                                                    u16* __restrict__ Hb, int nrows) {
    __shared__ u16 Bs[128 * 136];
    int tid = threadIdx.x;
    #pragma unroll
    for (int i = 0; i < 8; i++) {
        int c = i * 256 + tid;          // 16B chunk id; 2048 chunks = 32 KB
        int n = c >> 4, cc = c & 15;
        *(uint4*)&Bs[n * 136 + cc * 8] = ((const uint4*)Wt)[c];
    }
    __syncthreads();
    int wave = tid >> 6, lane = tid & 63;
    int quad = lane >> 4, l16 = lane & 15;
    int rowbase = blockIdx.x * 64 + wave * 16;
    int arow = rowbase + l16; if (arow >= nrows) arow = nrows - 1;  // clamp (store guarded)
    const AT* aptr = Ab + (size_t)arow * 128 + quad * 8;
    f32x4 acc[8];
    #pragma unroll
    for (int t = 0; t < 8; t++) acc[t] = (f32x4){0.f, 0.f, 0.f, 0.f};
    #pragma unroll
    for (int kk = 0; kk < 4; kk++) {
        bf16x8 a = load_a_frag<AT>(aptr + kk * 32);
        #pragma unroll
        for (int t = 0; t < 8; t++) {
            bf16x8 b = *(const bf16x8*)&Bs[(size_t)(t * 16 + l16) * 136 + kk * 32 + quad * 8];
            acc[t] = __builtin_amdgcn_mfma_f32_16x16x32_bf16(a, b, acc[t], 0, 0, 0);
        }
    }
    #pragma unroll
    for (int r = 0; r < 4; r++) {
        int orow = rowbase + quad * 4 + r;
        if (orow < nrows) {
            #pragma unroll
            for (int t = 0; t < 8; t++)
                Hb[(size_t)orow * 128 + t * 16 + l16] = (u16)f2bf(acc[t][r]);
        }
    }
}

// ---------------- final: bf16 [N,128] @ W3t[48n][128k] + b3, log_softmax -> fp32 [N,40] ----------

__global__ __launch_bounds__(256) void gemm40_lsm(const u16* __restrict__ G,
                                                  const u16* __restrict__ W3t,
                                                  const float* __restrict__ b3,
                                                  float* __restrict__ out, int nrows) {
    __shared__ u16 Bs[48 * 136];
    __shared__ float Ls[4][16][48];
    int tid = threadIdx.x;
    for (int c = tid; c < 768; c += 256) {          // 48*128*2B = 768 16B chunks
        int n = c >> 4, cc = c & 15;
        *(uint4*)&Bs[n * 136 + cc * 8] = ((const uint4*)W3t)[c];
    }
    __syncthreads();
    int wave = tid >> 6, lane = tid & 63;
    int quad = lane >> 4, l16 = lane & 15;
    int rowbase = blockIdx.x * 64 + wave * 16;
    int arow = rowbase + l16; if (arow >= nrows) arow = nrows - 1;
    const u16* aptr = G + (size_t)arow * 128 + quad * 8;
    f32x4 acc[3];
    #pragma unroll
    for (int t = 0; t < 3; t++) acc[t] = (f32x4){0.f, 0.f, 0.f, 0.f};
    #pragma unroll
    for (int kk = 0; kk < 4; kk++) {
        bf16x8 a = *(const bf16x8*)(aptr + kk * 32);
        #pragma unroll
        for (int t = 0; t < 3; t++) {
            bf16x8 b = *(const bf16x8*)&Bs[(size_t)(t * 16 + l16) * 136 + kk * 32 + quad * 8];
            acc[t] = __builtin_amdgcn_mfma_f32_16x16x32_bf16(a, b, acc[t], 0, 0, 0);
        }
    }
    #pragma unroll
    for (int r = 0; r < 4; r++)
        #pragma unroll
        for (int t = 0; t < 3; t++)
            Ls[wave][quad * 4 + r][t * 16 + l16] = acc[t][r];
    __syncthreads();
    float bval = (lane < N_CLASSES) ? b3[lane] : 0.f;
    for (int r = 0; r < 16; r++) {
        int row = rowbase + r;
        float v = (lane < N_CLASSES) ? Ls[wave][r][lane] + bval : -INFINITY;
        float m = v;
        #pragma unroll
        for (int off = 32; off > 0; off >>= 1) m = fmaxf(m, __shfl_xor(m, off));
        float e = (lane < N_CLASSES) ? expf(v - m) : 0.f;
        #pragma unroll
        for (int off = 32; off > 0; off >>= 1) e += __shfl_xor(e, off);
        float ls = logf(e);
        if (lane < N_CLASSES && row < nrows)
            out[(size_t)row * N_CLASSES + lane] = v - m - ls;
    }
}

// ---------------- Aggregation (128-wide, bf16 in/out) ----------------
// out[i] = dinv[i] * sum_{s in adj(i)} dinv[s]*h[s] + dinv[i]^2*h[i] [+ bias, relu]
// (coef array eliminated; dinv[s] is a wave-uniform broadcast load per edge)

template <int BIAS_RELU>
__global__ void agg128_bf16(const u16* __restrict__ Hb, const int* __restrict__ rowptr,
                            const int* __restrict__ colidx,
                            const float* __restrict__ dinv, const float* __restrict__ bias,
                            u16* __restrict__ Ob, int nrows) {
    int wave = threadIdx.x >> 6;
    int lane = threadIdx.x & 63;
    int node = blockIdx.x * (blockDim.x >> 6) + wave;
    if (node >= nrows) return;
    const u32* H32 = (const u32*)Hb;   // 2 bf16 per u32; row stride = 64 u32
    int beg = rowptr[node], end = rowptr[node + 1];
    float di = dinv[node];
    u32 hv = H32[(size_t)node * 64 + lane];
    // accumulate sum of dinv[s]*h[s]; self-loop folded as di*h[node]
    float ax = di * bflo(hv), ay = di * bfhi(hv);
    int j = beg;
    for (; j + 4 <= end; j += 4) {
        int s0 = colidx[j], s1 = colidx[j + 1], s2 = colidx[j + 2], s3 = colidx[j + 3];
        float c0 = dinv[s0], c1 = dinv[s1], c2 = dinv[s2], c3 = dinv[s3];
        u32 v0 = H32[(size_t)s0 * 64 + lane];
        u32 v1 = H32[(size_t)s1 * 64 + lane];
        u32 v2 = H32[(size_t)s2 * 64 + lane];
        u32 v3 = H32[(size_t)s3 * 64 + lane];
        ax += c0 * bflo(v0); ay += c0 * bfhi(v0);
        ax += c1 * bflo(v1); ay += c1 * bfhi(v1);
        ax += c2 * bflo(v2); ay += c2 * bfhi(v2);
        ax += c3 * bflo(v3); ay += c3 * bfhi(v3);
    }
    for (; j < end; j++) {
        int s = colidx[j];
        float c = dinv[s];
        u32 v = H32[(size_t)s * 64 + lane];
        ax += c * bflo(v); ay += c * bfhi(v);
    }
    ax *= di; ay *= di;
    if (BIAS_RELU) {
        float2 b = ((const float2*)bias)[lane];
        ax = fmaxf(ax + b.x, 0.f);
        ay = fmaxf(ay + b.y, 0.f);
    }
    ((u32*)Ob)[(size_t)node * 64 + lane] = packbf2(ax, ay);
}

// ---------------- launch ----------------

extern "C" void kernel_launch(void* const* d_in, const int* in_sizes, int n_in,
                              void* d_out, int out_size, void* d_ws, size_t ws_size,
                              hipStream_t stream) {
    const float* x  = (const float*)d_in[0];
    const int*   ei = (const int*)d_in[1];
    const float* W1 = (const float*)d_in[2];
    const float* b1 = (const float*)d_in[3];
    const float* W2 = (const float*)d_in[4];
    const float* b2 = (const float*)d_in[5];
    const float* W3 = (const float*)d_in[6];
    const float* b3 = (const float*)d_in[7];
    float* out = (float*)d_out;

    int N = in_sizes[0] / N_FEAT;
    int E = in_sizes[1] / 2;
    const int* src = ei;
    const int* dst = ei + E;

    char* ws = (char*)d_ws;
    size_t off = 0;
    auto alloc = [&](size_t bytes) -> char* {
        char* p = ws + off;
        off = (off + bytes + 255) & ~(size_t)255;
        return p;
    };
    int*   deg_cnt = (int*)  alloc((size_t)N * 4);
    int*   counter = (int*)  alloc((size_t)N * 4);
    float* dinv    = (float*)alloc((size_t)N * 4);
    int*   rowptr  = (int*)  alloc((size_t)(N + 1) * 4);
    int*   colidx  = (int*)  alloc((size_t)E * 4);
    int*   bsum    = (int*)  alloc((size_t)1024 * 4);
    int*   boff    = (int*)  alloc((size_t)1024 * 4);
    u16*   W1t     = (u16*)  alloc((size_t)128 * 128 * 2);
    u16*   W2t     = (u16*)  alloc((size_t)128 * 128 * 2);
    u16*   W3t     = (u16*)  alloc((size_t)48 * 128 * 2);
    u16*   Hbuf    = (u16*)  alloc((size_t)N * 128 * 2);   // gemm out (gather src)
    u16*   Abuf    = (u16*)  alloc((size_t)N * 128 * 2);   // agg out (layer 1)
    u16*   A2buf   = (u16*)  alloc((size_t)N * 128 * 2);   // agg out (layer 2)

    int tpb = 256;
    int gN = (N + tpb - 1) / tpb;
    int gE = (E + tpb - 1) / tpb;
    int nb = (N + 1023) / 1024;

    // Zero deg_cnt AND counter in one launch (span from actual pointers incl. 256B pad).
    int zspan = (int)(counter - deg_cnt) + N;
    zero_i32<<<(zspan + tpb - 1) / tpb, tpb, 0, stream>>>(deg_cnt, zspan);
    hist_kernel<<<gE, tpb, 0, stream>>>(dst, deg_cnt, E);
    scan1_kernel<<<nb, 256, 0, stream>>>(deg_cnt, rowptr, bsum, dinv, N);
    scan2_kernel<<<1, 1024, 0, stream>>>(bsum, boff, rowptr, nb, N);
    scan3_kernel<<<gN, tpb, 0, stream>>>(rowptr, boff, N);
    fill_kernel<<<gE, tpb, 0, stream>>>(src, dst, rowptr, counter, colidx, E);

    cvt_weights<<<(38912 + 255) / 256, 256, 0, stream>>>(W1, W2, W3, W1t, W2t, W3t);

    int gGemm = (N + 63) / 64;
    int gAgg  = (N + 3) / 4;   // 4 waves/block, 1 node/wave

    // layer 1 (A in fp32, converted in-register)
    gemm128_mfma<float><<<gGemm, 256, 0, stream>>>(x, W1t, Hbuf, N);
    agg128_bf16<1><<<gAgg, 256, 0, stream>>>(Hbuf, rowptr, colidx, dinv, b1, Abuf, N);
    // layer 2
    gemm128_mfma<u16><<<gGemm, 256, 0, stream>>>(Abuf, W2t, Hbuf, N);
    agg128_bf16<1><<<gAgg, 256, 0, stream>>>(Hbuf, rowptr, colidx, dinv, b2, A2buf, N);
    // layer 3 reordered by linearity: G = agg(A2); out = lsm(G @ W3 + b3)
    agg128_bf16<0><<<gAgg, 256, 0, stream>>>(A2buf, rowptr, colidx, dinv, b3, Hbuf, N);
    gemm40_lsm<<<gGemm, 256, 0, stream>>>(Hbuf, W3t, b3, out, N);
}

// Round 7
// 508.305 us; speedup vs baseline: 2.5082x; 1.0512x over previous
//
#include <hip/hip_runtime.h>
#include <math.h>

#define N_FEAT 128
#define N_CLASSES 40
#define BSCAT 256   // blocks for bucket histogram/scatter

typedef unsigned short u16;
typedef unsigned int u32;
typedef short bf16x8 __attribute__((ext_vector_type(8)));
typedef float f32x4 __attribute__((ext_vector_type(4)));

// ---- bf16 helpers ----
__device__ __forceinline__ u32 f2bf(float f) {
    u32 u = __float_as_uint(f);
    return (u + 0x7fffu + ((u >> 16) & 1u)) >> 16;
}
__device__ __forceinline__ u32 packbf2(float lo, float hi) {
    return f2bf(lo) | (f2bf(hi) << 16);
}
__device__ __forceinline__ float bflo(u32 v) { return __uint_as_float(v << 16); }
__device__ __forceinline__ float bfhi(u32 v) { return __uint_as_float(v & 0xffff0000u); }

// ---------------- basic ----------------

__global__ void zero_i32(int* __restrict__ p, int n) {
    int i = blockIdx.x * blockDim.x + threadIdx.x;
    if (i < n) p[i] = 0;
}

__global__ void hist_kernel(const int* __restrict__ dst, int* __restrict__ cnt, int E) {
    int e = blockIdx.x * blockDim.x + threadIdx.x;
    if (e < E) atomicAdd(&cnt[dst[e]], 1);
}

// ---------------- hierarchical scan (shared by rowptr and bucket-hist scans) ----------------
// scan1: per-block 1024-elem scan (+optional dinv from counts); scan2: block sums; scan3: add.

__global__ void scan1_kernel(const int* __restrict__ cnt, int* __restrict__ outp,
                             int* __restrict__ bsum, float* __restrict__ dinv, int n) {
    __shared__ int part[256];
    int b = blockIdx.x;
    int t = threadIdx.x;
    int base = b * 1024 + t * 4;
    int v0 = 0, v1 = 0, v2 = 0, v3 = 0;
    if (base + 3 < n) {
        int4 v = *(const int4*)&cnt[base];
        v0 = v.x; v1 = v.y; v2 = v.z; v3 = v.w;
    } else {
        if (base + 0 < n) v0 = cnt[base + 0];
        if (base + 1 < n) v1 = cnt[base + 1];
        if (base + 2 < n) v2 = cnt[base + 2];
        if (base + 3 < n) v3 = cnt[base + 3];
    }
    if (dinv) {
        if (base + 0 < n) dinv[base + 0] = rsqrtf((float)(v0 + 1));
        if (base + 1 < n) dinv[base + 1] = rsqrtf((float)(v1 + 1));
        if (base + 2 < n) dinv[base + 2] = rsqrtf((float)(v2 + 1));
        if (base + 3 < n) dinv[base + 3] = rsqrtf((float)(v3 + 1));
    }
    int s = v0 + v1 + v2 + v3;
    part[t] = s;
    __syncthreads();
    #pragma unroll
    for (int off = 1; off < 256; off <<= 1) {
        int mine = part[t];
        int other = (t >= off) ? part[t - off] : 0;
        __syncthreads();
        part[t] = mine + other;
        __syncthreads();
    }
    int excl = part[t] - s;
    if (base + 0 < n) outp[base + 0] = excl;
    if (base + 1 < n) outp[base + 1] = excl + v0;
    if (base + 2 < n) outp[base + 2] = excl + v0 + v1;
    if (base + 3 < n) outp[base + 3] = excl + v0 + v1 + v2;
    if (t == 255) bsum[b] = part[255];
}

__global__ void scan2_kernel(const int* __restrict__ bsum, int* __restrict__ boff,
                             int* __restrict__ outp, int nb, int n) {
    __shared__ int part[1024];
    int t = threadIdx.x;
    int s = (t < nb) ? bsum[t] : 0;
    part[t] = s;
    __syncthreads();
    for (int off = 1; off < 1024; off <<= 1) {
        int mine = part[t];
        int other = (t >= off) ? part[t - off] : 0;
        __syncthreads();
        part[t] = mine + other;
        __syncthreads();
    }
    if (t < nb) boff[t] = part[t] - s;
    if (t == 1023) outp[n] = part[1023];
}

__global__ void scan3_kernel(int* __restrict__ outp, const int* __restrict__ boff, int n) {
    int i = blockIdx.x * blockDim.x + threadIdx.x;
    if (i < n) outp[i] += boff[i >> 10];
}

// ---------------- bucketed CSR build ----------------
// Phase A: bucket edges by dst>>8. Per-(block,bucket) output regions are private and
// written sequentially -> full 64B lines (vs. 1 line per 4B with the old atomic scatter).

__global__ void ehist_kernel(const int* __restrict__ dst, int* __restrict__ hist,
                             int E, int chunk, int NB) {
    __shared__ int cnt[512];
    int b = blockIdx.x, t = threadIdx.x;
    for (int i = t; i < NB; i += 256) cnt[i] = 0;
    __syncthreads();
    int beg = b * chunk, end = min(E, beg + chunk);
    for (int e = beg + t; e < end; e += 256) atomicAdd(&cnt[dst[e] >> 8], 1);
    __syncthreads();
    int B = gridDim.x;
    for (int d = t; d < NB; d += 256) hist[d * B + b] = cnt[d];
}

__global__ void scatterA_kernel(const int* __restrict__ src, const int* __restrict__ dst,
                                const int* __restrict__ histscan, uint2* __restrict__ pairs,
                                int E, int chunk, int NB) {
    __shared__ int base[512];
    int b = blockIdx.x, t = threadIdx.x;
    int B = gridDim.x;
    for (int d = t; d < NB; d += 256) base[d] = histscan[d * B + b];
    __syncthreads();
    int beg = b * chunk, end = min(E, beg + chunk);
    for (int e = beg + t; e < end; e += 256) {
        int dd = dst[e];
        int pos = atomicAdd(&base[dd >> 8], 1);
        pairs[pos] = make_uint2((u32)src[e], (u32)dd);
    }
}

// Phase B: one block per bucket; exact grouping via 256-entry LDS counters.
// colidx writes land in a ~25KB contiguous window per bucket (L2-hot, full lines).
__global__ void fillB_kernel(const uint2* __restrict__ pairs, const int* __restrict__ histscan,
                             const int* __restrict__ rowptr, int* __restrict__ colidx,
                             int E, int NB, int B) {
    __shared__ int lcnt[256];
    int d = blockIdx.x, t = threadIdx.x;
    lcnt[t] = 0;
    __syncthreads();
    int beg = histscan[d * B];
    int end = (d + 1 < NB) ? histscan[(d + 1) * B] : E;
    for (int e = beg + t; e < end; e += 256) {
        uint2 p = pairs[e];
        int dd = (int)p.y;
        int pos = rowptr[dd] + atomicAdd(&lcnt[dd & 255], 1);
        colidx[pos] = (int)p.x;
    }
}

// ---------------- weight conversions (one launch) ----------------

__global__ void cvt_weights(const float* __restrict__ W1, const float* __restrict__ W2,
                            const float* __restrict__ W3,
                            u16* __restrict__ W1t, u16* __restrict__ W2t, u16* __restrict__ W3t) {
    int i = blockIdx.x * blockDim.x + threadIdx.x;
    if (i < 16384) {
        int n = i & 127, k = i >> 7;
        W1t[(size_t)n * 128 + k] = (u16)f2bf(W1[(size_t)k * 128 + n]);
    } else if (i < 32768) {
        int j = i - 16384;
        int n = j & 127, k = j >> 7;
        W2t[(size_t)n * 128 + k] = (u16)f2bf(W2[(size_t)k * 128 + n]);
    } else if (i < 32768 + 6144) {
        int j = i - 32768;
        int k = j & 127, n = j >> 7;
        W3t[(size_t)n * 128 + k] = (n < N_CLASSES) ? (u16)f2bf(W3[(size_t)k * N_CLASSES + n]) : (u16)0;
    }
}

// ---------------- MFMA GEMM: [N,128] @ Wt[128n][128k] -> bf16 [N,128] ----------------

template <typename AT>
__device__ __forceinline__ bf16x8 load_a_frag(const AT* aptr);

template <>
__device__ __forceinline__ bf16x8 load_a_frag<u16>(const u16* aptr) {
    return *(const bf16x8*)aptr;
}
template <>
__device__ __forceinline__ bf16x8 load_a_frag<float>(const float* aptr) {
    float4 lo = *(const float4*)aptr;
    float4 hi = *(const float4*)(aptr + 4);
    union { u32 u[4]; bf16x8 v; } r;
    r.u[0] = packbf2(lo.x, lo.y);
    r.u[1] = packbf2(lo.z, lo.w);
    r.u[2] = packbf2(hi.x, hi.y);
    r.u[3] = packbf2(hi.z, hi.w);
    return r.v;
}

template <typename AT>
__global__ __launch_bounds__(256) void gemm128_mfma(const AT* __restrict__ Ab,
                                                    const u16* __restrict__ Wt,
                                                    u16* __restrict__ Hb, int nrows) {
    __shared__ u16 Bs[128 * 136];
    int tid = threadIdx.x;
    #pragma unroll
    for (int i = 0; i < 8; i++) {
        int c = i * 256 + tid;
        int n = c >> 4, cc = c & 15;
        *(uint4*)&Bs[n * 136 + cc * 8] = ((const uint4*)Wt)[c];
    }
    __syncthreads();
    int wave = tid >> 6, lane = tid & 63;
    int quad = lane >> 4, l16 = lane & 15;
    int rowbase = blockIdx.x * 64 + wave * 16;
    int arow = rowbase + l16; if (arow >= nrows) arow = nrows - 1;
    const AT* aptr = Ab + (size_t)arow * 128 + quad * 8;
    f32x4 acc[8];
    #pragma unroll
    for (int t = 0; t < 8; t++) acc[t] = (f32x4){0.f, 0.f, 0.f, 0.f};
    #pragma unroll
    for (int kk = 0; kk < 4; kk++) {
        bf16x8 a = load_a_frag<AT>(aptr + kk * 32);
        #pragma unroll
        for (int t = 0; t < 8; t++) {
            bf16x8 b = *(const bf16x8*)&Bs[(size_t)(t * 16 + l16) * 136 + kk * 32 + quad * 8];
            acc[t] = __builtin_amdgcn_mfma_f32_16x16x32_bf16(a, b, acc[t], 0, 0, 0);
        }
    }
    #pragma unroll
    for (int r = 0; r < 4; r++) {
        int orow = rowbase + quad * 4 + r;
        if (orow < nrows) {
            #pragma unroll
            for (int t = 0; t < 8; t++)
                Hb[(size_t)orow * 128 + t * 16 + l16] = (u16)f2bf(acc[t][r]);
        }
    }
}

// ---------------- final: bf16 [N,128] @ W3t[48n][128k] + b3, log_softmax -> fp32 [N,40] --------

__global__ __launch_bounds__(256) void gemm40_lsm(const u16* __restrict__ G,
                                                  const u16* __restrict__ W3t,
                                                  const float* __restrict__ b3,
                                                  float* __restrict__ out, int nrows) {
    __shared__ u16 Bs[48 * 136];
    __shared__ float Ls[4][16][48];
    int tid = threadIdx.x;
    for (int c = tid; c < 768; c += 256) {
        int n = c >> 4, cc = c & 15;
        *(uint4*)&Bs[n * 136 + cc * 8] = ((const uint4*)W3t)[c];
    }
    __syncthreads();
    int wave = tid >> 6, lane = tid & 63;
    int quad = lane >> 4, l16 = lane & 15;
    int rowbase = blockIdx.x * 64 + wave * 16;
    int arow = rowbase + l16; if (arow >= nrows) arow = nrows - 1;
    const u16* aptr = G + (size_t)arow * 128 + quad * 8;
    f32x4 acc[3];
    #pragma unroll
    for (int t = 0; t < 3; t++) acc[t] = (f32x4){0.f, 0.f, 0.f, 0.f};
    #pragma unroll
    for (int kk = 0; kk < 4; kk++) {
        bf16x8 a = *(const bf16x8*)(aptr + kk * 32);
        #pragma unroll
        for (int t = 0; t < 3; t++) {
            bf16x8 b = *(const bf16x8*)&Bs[(size_t)(t * 16 + l16) * 136 + kk * 32 + quad * 8];
            acc[t] = __builtin_amdgcn_mfma_f32_16x16x32_bf16(a, b, acc[t], 0, 0, 0);
        }
    }
    #pragma unroll
    for (int r = 0; r < 4; r++)
        #pragma unroll
        for (int t = 0; t < 3; t++)
            Ls[wave][quad * 4 + r][t * 16 + l16] = acc[t][r];
    __syncthreads();
    float bval = (lane < N_CLASSES) ? b3[lane] : 0.f;
    for (int r = 0; r < 16; r++) {
        int row = rowbase + r;
        float v = (lane < N_CLASSES) ? Ls[wave][r][lane] + bval : -INFINITY;
        float m = v;
        #pragma unroll
        for (int off = 32; off > 0; off >>= 1) m = fmaxf(m, __shfl_xor(m, off));
        float e = (lane < N_CLASSES) ? expf(v - m) : 0.f;
        #pragma unroll
        for (int off = 32; off > 0; off >>= 1) e += __shfl_xor(e, off);
        float ls = logf(e);
        if (lane < N_CLASSES && row < nrows)
            out[(size_t)row * N_CLASSES + lane] = v - m - ls;
    }
}

// ---------------- Aggregation (128-wide, bf16 in/out) ----------------
// out[i] = dinv[i] * sum_{s in adj(i)} dinv[s]*h[s] + dinv[i]^2*h[i] [+ bias, relu]

template <int BIAS_RELU>
__global__ void agg128_bf16(const u16* __restrict__ Hb, const int* __restrict__ rowptr,
                            const int* __restrict__ colidx,
                            const float* __restrict__ dinv, const float* __restrict__ bias,
                            u16* __restrict__ Ob, int nrows) {
    int wave = threadIdx.x >> 6;
    int lane = threadIdx.x & 63;
    int node = blockIdx.x * (blockDim.x >> 6) + wave;
    if (node >= nrows) return;
    const u32* H32 = (const u32*)Hb;
    int beg = rowptr[node], end = rowptr[node + 1];
    float di = dinv[node];
    u32 hv = H32[(size_t)node * 64 + lane];
    float ax = di * bflo(hv), ay = di * bfhi(hv);
    int j = beg;
    for (; j + 4 <= end; j += 4) {
        int s0 = colidx[j], s1 = colidx[j + 1], s2 = colidx[j + 2], s3 = colidx[j + 3];
        float c0 = dinv[s0], c1 = dinv[s1], c2 = dinv[s2], c3 = dinv[s3];
        u32 v0 = H32[(size_t)s0 * 64 + lane];
        u32 v1 = H32[(size_t)s1 * 64 + lane];
        u32 v2 = H32[(size_t)s2 * 64 + lane];
        u32 v3 = H32[(size_t)s3 * 64 + lane];
        ax += c0 * bflo(v0); ay += c0 * bfhi(v0);
        ax += c1 * bflo(v1); ay += c1 * bfhi(v1);
        ax += c2 * bflo(v2); ay += c2 * bfhi(v2);
        ax += c3 * bflo(v3); ay += c3 * bfhi(v3);
    }
    for (; j < end; j++) {
        int s = colidx[j];
        float c = dinv[s];
        u32 v = H32[(size_t)s * 64 + lane];
        ax += c * bflo(v); ay += c * bfhi(v);
    }
    ax *= di; ay *= di;
    if (BIAS_RELU) {
        float2 b = ((const float2*)bias)[lane];
        ax = fmaxf(ax + b.x, 0.f);
        ay = fmaxf(ay + b.y, 0.f);
    }
    ((u32*)Ob)[(size_t)node * 64 + lane] = packbf2(ax, ay);
}

// ---------------- launch ----------------

extern "C" void kernel_launch(void* const* d_in, const int* in_sizes, int n_in,
                              void* d_out, int out_size, void* d_ws, size_t ws_size,
                              hipStream_t stream) {
    const float* x  = (const float*)d_in[0];
    const int*   ei = (const int*)d_in[1];
    const float* W1 = (const float*)d_in[2];
    const float* b1 = (const float*)d_in[3];
    const float* W2 = (const float*)d_in[4];
    const float* b2 = (const float*)d_in[5];
    const float* W3 = (const float*)d_in[6];
    const float* b3 = (const float*)d_in[7];
    float* out = (float*)d_out;

    int N = in_sizes[0] / N_FEAT;
    int E = in_sizes[1] / 2;
    const int* src = ei;
    const int* dst = ei + E;

    char* ws = (char*)d_ws;
    size_t off = 0;
    auto alloc = [&](size_t bytes) -> char* {
        char* p = ws + off;
        off = (off + bytes + 255) & ~(size_t)255;
        return p;
    };
    int NB = (N + 255) >> 8;                 // coarse buckets (dst>>8)
    int n2 = NB * BSCAT;                     // bucket-hist elements

    int*   deg_cnt  = (int*)  alloc((size_t)N * 4);
    float* dinv     = (float*)alloc((size_t)N * 4);
    int*   rowptr   = (int*)  alloc((size_t)(N + 1) * 4);
    int*   colidx   = (int*)  alloc((size_t)E * 4);
    int*   bsum     = (int*)  alloc((size_t)1024 * 4);
    int*   boff     = (int*)  alloc((size_t)1024 * 4);
    int*   hist     = (int*)  alloc((size_t)n2 * 4);
    int*   histscan = (int*)  alloc((size_t)(n2 + 1) * 4);
    int*   bsum2    = (int*)  alloc((size_t)1024 * 4);
    int*   boff2    = (int*)  alloc((size_t)1024 * 4);
    uint2* pairs    = (uint2*)alloc((size_t)E * 8);
    u16*   W1t      = (u16*)  alloc((size_t)128 * 128 * 2);
    u16*   W2t      = (u16*)  alloc((size_t)128 * 128 * 2);
    u16*   W3t      = (u16*)  alloc((size_t)48 * 128 * 2);
    u16*   Hbuf     = (u16*)  alloc((size_t)N * 128 * 2);
    u16*   Abuf     = (u16*)  alloc((size_t)N * 128 * 2);
    u16*   A2buf    = (u16*)  alloc((size_t)N * 128 * 2);

    int tpb = 256;
    int gN = (N + tpb - 1) / tpb;
    int gE = (E + tpb - 1) / tpb;
    int nb = (N + 1023) / 1024;
    int nb2 = (n2 + 1023) / 1024;
    int chunk = (E + BSCAT - 1) / BSCAT;

    // degree + rowptr + dinv
    zero_i32<<<gN, tpb, 0, stream>>>(deg_cnt, N);
    hist_kernel<<<gE, tpb, 0, stream>>>(dst, deg_cnt, E);
    scan1_kernel<<<nb, 256, 0, stream>>>(deg_cnt, rowptr, bsum, dinv, N);
    scan2_kernel<<<1, 1024, 0, stream>>>(bsum, boff, rowptr, nb, N);
    scan3_kernel<<<gN, tpb, 0, stream>>>(rowptr, boff, N);

    // bucketed CSR fill (replaces random 4B scatter)
    ehist_kernel<<<BSCAT, 256, 0, stream>>>(dst, hist, E, chunk, NB);
    scan1_kernel<<<nb2, 256, 0, stream>>>(hist, histscan, bsum2, nullptr, n2);
    scan2_kernel<<<1, 1024, 0, stream>>>(bsum2, boff2, histscan, nb2, n2);
    scan3_kernel<<<(n2 + tpb - 1) / tpb, tpb, 0, stream>>>(histscan, boff2, n2);
    scatterA_kernel<<<BSCAT, 256, 0, stream>>>(src, dst, histscan, pairs, E, chunk, NB);
    fillB_kernel<<<NB, 256, 0, stream>>>(pairs, histscan, rowptr, colidx, E, NB, BSCAT);

    cvt_weights<<<(38912 + 255) / 256, 256, 0, stream>>>(W1, W2, W3, W1t, W2t, W3t);

    int gGemm = (N + 63) / 64;
    int gAgg  = (N + 3) / 4;

    // layer 1 (A in fp32, converted in-register)
    gemm128_mfma<float><<<gGemm, 256, 0, stream>>>(x, W1t, Hbuf, N);
    agg128_bf16<1><<<gAgg, 256, 0, stream>>>(Hbuf, rowptr, colidx, dinv, b1, Abuf, N);
    // layer 2
    gemm128_mfma<u16><<<gGemm, 256, 0, stream>>>(Abuf, W2t, Hbuf, N);
    agg128_bf16<1><<<gAgg, 256, 0, stream>>>(Hbuf, rowptr, colidx, dinv, b2, A2buf, N);
    // layer 3 reordered by linearity: G = agg(A2); out = lsm(G @ W3 + b3)
    agg128_bf16<0><<<gAgg, 256, 0, stream>>>(A2buf, rowptr, colidx, dinv, b3, Hbuf, N);
    gemm40_lsm<<<gGemm, 256, 0, stream>>>(Hbuf, W3t, b3, out, N);
}